// Round 17
// baseline (170.908 us; speedup 1.0000x reference)
//
#include <hip/hip_runtime.h>
#include <math.h>

#define S_LEN 1024
#define NH 8

typedef __attribute__((ext_vector_type(8))) short bf16x8;
typedef __attribute__((ext_vector_type(4))) float f32x4;

__device__ __forceinline__ float sp_softplus(float x) {
    return fmaxf(x, 0.f) + log1pf(expf(-fabsf(x)));
}

__device__ __forceinline__ unsigned short bfu(float f) {
    unsigned u = __float_as_uint(f);
    unsigned r = (u + 0x7FFFu + ((u >> 16) & 1u)) >> 16;   // RNE
    return (unsigned short)r;
}

// ============ PREP kernel: weight tcast + cs table + wukb cast ===============
struct PREP {
    const float *raw_delta, *wuk;
    const float *wdkv, *wdq, *wkr, *wuq, *wqr, *wuv, *wout;
    float *csc, *css;
    unsigned short *wdkvT, *wdqT, *wkrT, *wuqT, *wqrT, *wuvT, *woutT, *wukb;
};

__global__ __launch_bounds__(256) void prep_kernel(PREP f)
{
    __shared__ unsigned short tile[64][65];
    int bx = blockIdx.x;
    if (bx < 464) {
        int b = bx;
        const float* srcs[7] = {f.wdkv, f.wdq, f.wkr, f.wuq, f.wqr, f.wuv, f.wout};
        unsigned short* dsts[7] = {f.wdkvT, f.wdqT, f.wkrT, f.wuqT, f.wqrT, f.wuvT, f.woutT};
        const int Ns[7]   = {256, 512, 32, 512, 256, 512, 1024};
        const int Klds[7] = {1024, 1024, 1024, 512, 512, 256, 512};
        const int Ntl[7]  = {4, 8, 1, 8, 4, 8, 16};
        const int bst[8]  = {0, 64, 192, 208, 272, 304, 336, 464};
        int e = 0;
        #pragma unroll
        for (int i = 1; i < 7; ++i) if (b >= bst[i]) e = i;
        int lb = b - bst[e];
        int nt = lb % Ntl[e], kt = lb / Ntl[e];
        const float* src = srcs[e];
        unsigned short* dst = dsts[e];
        int N = Ns[e], Kld = Klds[e];
        int k0 = kt * 64, n0 = nt * 64;
        int t = threadIdx.x;
        int c = t & 63, r4 = t >> 6;
        #pragma unroll
        for (int it = 0; it < 16; ++it) {
            int r = it * 4 + r4;
            float v = (n0 + c < N) ? src[(long)(k0 + r) * N + n0 + c] : 0.f;
            tile[r][c] = bfu(v);
        }
        __syncthreads();
        int wq = t & 7;
        #pragma unroll
        for (int itw = 0; itw < 2; ++itw) {
            int wr = itw * 32 + (t >> 3);
            if (n0 + wr < N) {
                unsigned short v[8];
                #pragma unroll
                for (int j = 0; j < 8; ++j) v[j] = tile[wq * 8 + j][wr];
                *(uint4*)(dst + (long)(n0 + wr) * Kld + k0 + wq * 8) = *(uint4*)v;
            }
        }
    } else if (bx < 472) {
        int idx = (bx - 464) * 256 + threadIdx.x;
        int j = idx >> 4, i = idx & 15;
        float rd = f.raw_delta[i];
        float delta = -6.283185307179586f * (1.f / (1.f + expf(-rd)));
        float th = exp2f(-(float)i * 0.83048202372184f);
        float ang = (float)j * th + delta;
        float sv, cv;
        sincosf(ang, &sv, &cv);
        f.csc[idx] = cv;
        f.css[idx] = sv;
    } else {
        int idx = (bx - 472) * 256 + threadIdx.x;
        f.wukb[idx] = bfu(f.wuk[idx]);
    }
}

// ============ bf16 MFMA GEMM body (shared) ===================================
__device__ __forceinline__ void mgemm_body(
    const float* A, const unsigned short* B, float* C,
    int lda, int ldb, int ldc, int K, int N, int obf, int m0, int n0, char* smem)
{
    unsigned short (*As)[40] = (unsigned short(*)[40])smem;
    unsigned short (*Bs)[40] = (unsigned short(*)[40])(smem + 5120);
    int t = threadIdx.x;
    int srow = t >> 2, skq = t & 3;
    int wid = t >> 6, l = t & 63;
    int wm = (wid >> 1) * 32, wn = (wid & 1) * 32;
    int fr = l & 15, fk = (l >> 4) * 8;
    bool bok = (n0 + srow) < N;

    f32x4 acc00 = {0.f, 0.f, 0.f, 0.f};
    f32x4 acc01 = {0.f, 0.f, 0.f, 0.f};
    f32x4 acc10 = {0.f, 0.f, 0.f, 0.f};
    f32x4 acc11 = {0.f, 0.f, 0.f, 0.f};

    for (int k0 = 0; k0 < K; k0 += 32) {
        {
            const float* ap = A + (long)(m0 + srow) * lda + k0 + skq * 8;
            float4 v0 = *(const float4*)ap;
            float4 v1 = *(const float4*)(ap + 4);
            unsigned short* d = &As[srow][skq * 8];
            d[0] = bfu(v0.x); d[1] = bfu(v0.y); d[2] = bfu(v0.z); d[3] = bfu(v0.w);
            d[4] = bfu(v1.x); d[5] = bfu(v1.y); d[6] = bfu(v1.z); d[7] = bfu(v1.w);
        }
        {
            uint4 bv = make_uint4(0u, 0u, 0u, 0u);
            if (bok) bv = *(const uint4*)(B + (long)(n0 + srow) * ldb + k0 + skq * 8);
            *(uint4*)&Bs[srow][skq * 8] = bv;
        }
        __syncthreads();
        bf16x8 a0 = *(bf16x8*)&As[wm + fr][fk];
        bf16x8 a1 = *(bf16x8*)&As[wm + 16 + fr][fk];
        bf16x8 b0 = *(bf16x8*)&Bs[wn + fr][fk];
        bf16x8 b1 = *(bf16x8*)&Bs[wn + 16 + fr][fk];
        acc00 = __builtin_amdgcn_mfma_f32_16x16x32_bf16(a0, b0, acc00, 0, 0, 0);
        acc01 = __builtin_amdgcn_mfma_f32_16x16x32_bf16(a0, b1, acc01, 0, 0, 0);
        acc10 = __builtin_amdgcn_mfma_f32_16x16x32_bf16(a1, b0, acc10, 0, 0, 0);
        acc11 = __builtin_amdgcn_mfma_f32_16x16x32_bf16(a1, b1, acc11, 0, 0, 0);
        __syncthreads();
    }
    int crow = (l >> 4) * 4;
    int col0 = n0 + wn + fr, col1 = n0 + wn + 16 + fr;
    if (obf) {
        unsigned short* Cu = (unsigned short*)C;
        if (col0 < N) {
            #pragma unroll
            for (int r = 0; r < 4; ++r) {
                Cu[(long)(m0 + wm + crow + r) * ldc + col0]      = bfu(acc00[r]);
                Cu[(long)(m0 + wm + 16 + crow + r) * ldc + col0] = bfu(acc10[r]);
            }
        }
        if (col1 < N) {
            #pragma unroll
            for (int r = 0; r < 4; ++r) {
                Cu[(long)(m0 + wm + crow + r) * ldc + col1]      = bfu(acc01[r]);
                Cu[(long)(m0 + wm + 16 + crow + r) * ldc + col1] = bfu(acc11[r]);
            }
        }
    } else {
        if (col0 < N) {
            #pragma unroll
            for (int r = 0; r < 4; ++r) {
                C[(long)(m0 + wm + crow + r) * ldc + col0]      = acc00[r];
                C[(long)(m0 + wm + 16 + crow + r) * ldc + col0] = acc10[r];
            }
        }
        if (col1 < N) {
            #pragma unroll
            for (int r = 0; r < 4; ++r) {
                C[(long)(m0 + wm + crow + r) * ldc + col1]      = acc01[r];
                C[(long)(m0 + wm + 16 + crow + r) * ldc + col1] = acc11[r];
            }
        }
    }
}

// ============ SELV: stage-1 value mgemm (208) + fp32 sel-GEMM (1152) =========
// MFMA-pipe (vproj) and VALU-pipe (sel fp32) waves co-schedule on each CU.
struct SELV {
    const float *x, *wqidx, *wkidx;
    const unsigned short *wdkvT, *wdqT, *wkrT;
    unsigned short* ckvb; float *cq, *xkr;
    float *qIP, *kIP;
};

__global__ __launch_bounds__(256) void selv_kernel(SELV g)
{
    __shared__ __align__(16) char smem[11008];
    int bx = blockIdx.x;
    if (bx < 208) {
        int xi = bx % 13, m0 = (bx / 13) * 64;
        if (xi < 4)       mgemm_body(g.x, g.wdkvT, (float*)g.ckvb, 1024, 1024, 256, 1024, 256, 1, m0, xi * 64, smem);
        else if (xi < 12) mgemm_body(g.x, g.wdqT,  g.cq,           1024, 1024, 512, 1024, 512, 0, m0, (xi - 4) * 64, smem);
        else              mgemm_body(g.x, g.wkrT,  g.xkr,          1024, 1024, 32,  1024, 32,  0, m0, 0, smem);
        return;
    }
    // fp32 sel-GEMM, bit-identical to r16's FRONT body
    float (*As)[16][18] = (float(*)[16][18])smem;                 // [2][16][18]
    float (*Bs)[16][68] = (float(*)[16][68])(smem + 2304);        // [2][16][68]
    int b = bx - 208;
    int gx = b % 18, gy = b / 18;
    int half = threadIdx.x >> 7;
    int t = threadIdx.x & 127;
    int u = gx * 2 + half;
    const float* B; float* C;
    int ldb, N, n0, kb;
    if (u < 32) {
        B = g.wqidx; ldb = 512; N = 512;
        C = g.qIP + (long)(u >> 3) * 524288;
        n0 = (u & 7) * 64;
        kb = (u >> 3) * 256;
    } else {
        B = g.wkidx; ldb = 64; N = 64;
        C = g.kIP + (long)(u - 32) * 65536;
        n0 = 0;
        kb = (u - 32) * 256;
    }
    int ke = kb + 256;
    int m0 = gy * 16;
    int ar = t >> 2, ak = t & 3;
    int bk = t >> 3, bn = t & 7;
    int ty = t >> 4, tx = t & 15;

    float4 aN = make_float4(0.f, 0.f, 0.f, 0.f);
    if (t < 64) aN = *(const float4*)(g.x + (long)(m0 + ar) * 1024 + kb + ak * 4);
    float4 b0 = *(const float4*)(B + (long)(kb + bk) * ldb + n0 + bn * 4);
    float4 b1 = *(const float4*)(B + (long)(kb + bk) * ldb + n0 + (bn + 8) * 4);
    float acc[2][4] = {};
    for (int k0 = kb; k0 < ke; k0 += 16) {
        if (t < 64) {
            As[half][ak * 4 + 0][ar] = aN.x;
            As[half][ak * 4 + 1][ar] = aN.y;
            As[half][ak * 4 + 2][ar] = aN.z;
            As[half][ak * 4 + 3][ar] = aN.w;
        }
        *(float4*)&Bs[half][bk][bn * 4] = b0;
        *(float4*)&Bs[half][bk][(bn + 8) * 4] = b1;
        __syncthreads();
        if (k0 + 16 < ke) {
            if (t < 64) aN = *(const float4*)(g.x + (long)(m0 + ar) * 1024 + (k0 + 16) + ak * 4);
            b0 = *(const float4*)(B + (long)(k0 + 16 + bk) * ldb + n0 + bn * 4);
            b1 = *(const float4*)(B + (long)(k0 + 16 + bk) * ldb + n0 + (bn + 8) * 4);
        }
        #pragma unroll
        for (int kk = 0; kk < 16; ++kk) {
            float2 a = *(float2*)&As[half][kk][ty * 2];
            float4 bb = *(float4*)&Bs[half][kk][tx * 4];
            acc[0][0] += a.x * bb.x; acc[0][1] += a.x * bb.y;
            acc[0][2] += a.x * bb.z; acc[0][3] += a.x * bb.w;
            acc[1][0] += a.y * bb.x; acc[1][1] += a.y * bb.y;
            acc[1][2] += a.y * bb.z; acc[1][3] += a.y * bb.w;
        }
        __syncthreads();
    }
    #pragma unroll
    for (int i = 0; i < 2; ++i) {
        float4 v = make_float4(acc[i][0], acc[i][1], acc[i][2], acc[i][3]);
        *(float4*)(C + (long)(m0 + ty * 2 + i) * N + n0 + tx * 4) = v;
    }
}

// ---- indexer body (fused split-K reduce; bit-identical) ---------------------
__device__ __forceinline__ void indexer_body(
    const float* qIP, const float* kIP, const float* w_idx, float* I,
    int b, char* smem)
{
    int sb = b % 16, tb = b / 16;
    if (sb * 64 > tb * 32 + 31) return;
    int t0 = tb * 32, s0 = sb * 64;
    float (*ksT)[68] = (float(*)[68])smem;
    float (*qs)[68]  = (float(*)[68])(smem + 17408);
    int t = threadIdx.x;
    {
        int r = t & 63, q = t >> 6;
        #pragma unroll
        for (int u = 0; u < 4; ++u) {
            int c4 = q * 4 + u;
            long off = (long)(s0 + r) * 64 + c4 * 4;
            float4 v = *(const float4*)(kIP + off);
            #pragma unroll
            for (int s = 1; s < 4; ++s) {
                float4 v2 = *(const float4*)(kIP + (long)s * 65536 + off);
                v.x += v2.x; v.y += v2.y; v.z += v2.z; v.w += v2.w;
            }
            ksT[c4 * 4 + 0][r] = v.x;
            ksT[c4 * 4 + 1][r] = v.y;
            ksT[c4 * 4 + 2][r] = v.z;
            ksT[c4 * 4 + 3][r] = v.w;
        }
    }
    int ty = t >> 4, tx = t & 15;
    float accI[2][4] = {};
    for (int h = 0; h < 8; ++h) {
        __syncthreads();
        {
            int r = t >> 3, q = t & 7;
            long base = (long)(t0 + r) * 512 + h * 64;
            #pragma unroll
            for (int half = 0; half < 2; ++half) {
                long off = base + (q + half * 8) * 4;
                float4 a = *(const float4*)(qIP + off);
                #pragma unroll
                for (int s = 1; s < 4; ++s) {
                    float4 a1 = *(const float4*)(qIP + (long)s * 524288 + off);
                    a.x += a1.x; a.y += a1.y; a.z += a1.z; a.w += a1.w;
                }
                *(float4*)&qs[r][(q + half * 8) * 4] = a;
            }
        }
        __syncthreads();
        float acc[2][4] = {};
        #pragma unroll
        for (int dc = 0; dc < 4; ++dc) {
            float a0[16], a1[16];
            #pragma unroll
            for (int u = 0; u < 4; ++u) {
                float4 v0 = *(float4*)&qs[ty * 2][dc * 16 + u * 4];
                float4 v1 = *(float4*)&qs[ty * 2 + 1][dc * 16 + u * 4];
                a0[u * 4 + 0] = v0.x; a0[u * 4 + 1] = v0.y; a0[u * 4 + 2] = v0.z; a0[u * 4 + 3] = v0.w;
                a1[u * 4 + 0] = v1.x; a1[u * 4 + 1] = v1.y; a1[u * 4 + 2] = v1.z; a1[u * 4 + 3] = v1.w;
            }
            #pragma unroll
            for (int kk = 0; kk < 16; ++kk) {
                int d = dc * 16 + kk;
                float4 bb = *(float4*)&ksT[d][tx * 4];
                acc[0][0] += a0[kk] * bb.x; acc[0][1] += a0[kk] * bb.y;
                acc[0][2] += a0[kk] * bb.z; acc[0][3] += a0[kk] * bb.w;
                acc[1][0] += a1[kk] * bb.x; acc[1][1] += a1[kk] * bb.y;
                acc[1][2] += a1[kk] * bb.z; acc[1][3] += a1[kk] * bb.w;
            }
        }
        float wh = w_idx[h];
        #pragma unroll
        for (int i = 0; i < 2; ++i)
            #pragma unroll
            for (int j = 0; j < 4; ++j)
                accI[i][j] += wh * fmaxf(acc[i][j], 0.f);
    }
    #pragma unroll
    for (int i = 0; i < 2; ++i) {
        float4 v = make_float4(accI[i][0], accI[i][1], accI[i][2], accI[i][3]);
        *(float4*)&I[(long)(t0 + ty * 2 + i) * 1024 + s0 + tx * 4] = v;
    }
}

// ---- topk body: full wave bitonic sort (bit-identical) ----------------------
__device__ __forceinline__ void topk_body(
    const float* I, int* idxout, int b)
{
    int t = b * 4 + (threadIdx.x >> 6);
    int lane = threadIdx.x & 63;
    int smin = max(0, t - 63);
    int w = min(64, t + 1);
    if (lane < w) idxout[t * 128 + lane] = smin + lane;
    for (int q = t + 1 + lane; q < 128; q += 64)
        idxout[t * 128 + q] = q;
    int f = max(0, t - 63);
    int m = min(f, 64);
    if (m == 0) return;
    const float* row = I + (long)t * 1024;

    unsigned long long key[16];
    #pragma unroll
    for (int g4 = 0; g4 < 4; ++g4) {
        float4 v = *(const float4*)(row + lane * 16 + g4 * 4);
        float vv[4] = {v.x, v.y, v.z, v.w};
        #pragma unroll
        for (int j = 0; j < 4; ++j) {
            int s = lane * 16 + g4 * 4 + j;
            unsigned long long k = 0ull;
            if (s < f) {
                unsigned u = __float_as_uint(vv[j]);
                unsigned ou = (u & 0x80000000u) ? ~u : (u | 0x80000000u);
                k = ((unsigned long long)ou << 32) | (0xFFFFFFFFu - (unsigned)s);
            }
            key[g4 * 4 + j] = k;
        }
    }

    #pragma unroll
    for (int km = 1; km <= 10; ++km) {
        #pragma unroll
        for (int jm = km - 1; jm >= 0; --jm) {
            if (jm >= 4) {
                int lmask = 1 << (jm - 4);
                #pragma unroll
                for (int r = 0; r < 16; ++r) {
                    unsigned long long other = __shfl_xor(key[r], lmask, 64);
                    int i = lane * 16 + r;
                    bool keep_max = (((i & (1 << km)) == 0) == ((i & (1 << jm)) == 0));
                    unsigned long long mx = key[r] > other ? key[r] : other;
                    unsigned long long mn = key[r] > other ? other : key[r];
                    key[r] = keep_max ? mx : mn;
                }
            } else {
                int rmask = 1 << jm;
                #pragma unroll
                for (int r = 0; r < 16; ++r) {
                    if ((r & rmask) == 0) {
                        int r2 = r | rmask;
                        int i = lane * 16 + r;
                        bool keep_max_low = ((i & (1 << km)) == 0);
                        unsigned long long a = key[r], b2 = key[r2];
                        unsigned long long mx = a > b2 ? a : b2;
                        unsigned long long mn = a > b2 ? b2 : a;
                        key[r]  = keep_max_low ? mx : mn;
                        key[r2] = keep_max_low ? mn : mx;
                    }
                }
            }
        }
    }

    if (lane < 4) {
        #pragma unroll
        for (int r = 0; r < 16; ++r) {
            int e = lane * 16 + r;
            if (e < m) {
                int s = (int)(0xFFFFFFFFu - (unsigned)(key[r] & 0xFFFFFFFFull));
                idxout[t * 128 + w + e] = s;
            }
        }
    }
}

// ============ S2C: stage-2 mgemm (192) + indexer (512) = 704 blocks ==========
struct S2C {
    const float* cq;
    const unsigned short *wuqT, *wqrT;
    float *qc, *qrp;
    const float *qIP, *kIP, *w_idx; float* I;
};

__global__ __launch_bounds__(256) void s2c_kernel(S2C g)
{
    __shared__ __align__(16) char smem[26112];
    int bx = blockIdx.x;
    if (bx < 192) {
        int xi = bx % 12, m0 = (bx / 12) * 64;
        if (xi < 8) mgemm_body(g.cq, g.wuqT, g.qc,  512, 512, 512, 512, 512, 0, m0, xi * 64, smem);
        else        mgemm_body(g.cq, g.wqrT, g.qrp, 512, 512, 256, 512, 256, 0, m0, (xi - 8) * 64, smem);
    } else {
        indexer_body(g.qIP, g.kIP, g.w_idx, g.I, bx - 192, smem);
    }
}

// ============ MID3: topk (256) + qabs (512) + pope (512) + mu (128) ==========
struct MID3 {
    const float* I; int* idxb;
    const float* qc; const unsigned short* wukb; float* qabs;
    const float *qrp, *raw_delta; float* qrr;
    const float* xkr; float* mu;
};

__global__ __launch_bounds__(256) void mid3_kernel(MID3 g)
{
    __shared__ __align__(16) char smem[10240];
    int b = blockIdx.x;
    int t = threadIdx.x;
    if (b < 256) {
        topk_body(g.I, g.idxb, b);
    } else if (b < 768) {
        int lb = b - 256;
        int h = lb >> 6, rem = lb & 63;
        int n0 = (rem >> 4) * 64, m0 = (rem & 15) * 64;
        mgemm_body(g.qc + h * 64, g.wukb + h * 64, g.qabs + h * 256,
                   512, 512, 2048, 64, 256, 0, m0, n0, smem);
    } else if (b < 1280) {
        int tq = (b - 768) * 2 + (t >> 7);
        int tt = t & 127;
        int h = tt >> 4, i = tt & 15;
        float rd = g.raw_delta[i];
        float delta = -6.283185307179586f * (1.f / (1.f + expf(-rd)));
        float th = exp2f(-(float)i * 0.83048202372184f);
        float ang = (float)tq * th + delta;
        float sv, cv;
        sincosf(ang, &sv, &cv);
        float m1 = sp_softplus(g.qrp[tq * 256 + h * 32 + i]);
        float m2 = sp_softplus(g.qrp[tq * 256 + h * 32 + 16 + i]);
        g.qrr[tq * 256 + h * 32 + i]      = m1 * cv - m2 * sv;
        g.qrr[tq * 256 + h * 32 + 16 + i] = m1 * sv + m2 * cv;
    } else {
        int i = (b - 1280) * 256 + t;
        g.mu[i] = sp_softplus(g.xkr[i]);
    }
}

// ============ generic routed mgemm kernel (L6/L7) ============================
struct MFG {
    const float* A[10]; const unsigned short* B[10]; float* C[10];
    int lda[10], ldb[10], ldc[10], K[10], N[10], obf[10];
    int tstart[11]; int ne;
};

__global__ __launch_bounds__(256) void mgemm(MFG mg)
{
    __shared__ __align__(16) char smem[10240];
    int bx = blockIdx.x, e = 0;
    #pragma unroll
    for (int i = 1; i < 10; ++i) if (i < mg.ne && bx >= mg.tstart[i]) e = i;
    mgemm_body(mg.A[e], mg.B[e], mg.C[e], mg.lda[e], mg.ldb[e], mg.ldc[e],
               mg.K[e], mg.N[e], mg.obf[e], blockIdx.y * 64,
               (bx - mg.tstart[e]) * 64, smem);
}

// -------- fused attention v8 (r12/r16 verbatim — 46.7 us) --------------------
__global__ __launch_bounds__(256) void attn_kernel(
    const float* __restrict__ qabs, const float* __restrict__ qrr,
    const unsigned short* __restrict__ ckvb, const float* __restrict__ mu,
    const float* __restrict__ csc, const float* __restrict__ css,
    const int* __restrict__ idxb, float* __restrict__ olat)
{
    __shared__ float sc[8][68];
    __shared__ float hs[16];
    __shared__ int idx_s[128];

    int t = blockIdx.x, tid = threadIdx.x;
    int w = tid >> 6, l = tid & 63;
    const float scale = 0.10206207261596575f;

    if (tid < 128) idx_s[tid] = idxb[t * 128 + tid];

    int hrow = l & 15;
    int kslice = (l >> 4) * 8;
    int hpv = l >> 3;
    int c8 = w * 64 + (l & 7) * 8;

    float mrun0 = -INFINITY, mrun1 = -INFINITY;
    float lrun0 = 0.f, lrun1 = 0.f;
    float acc0 = 0, acc1 = 0, acc2 = 0, acc3 = 0;
    float acc4 = 0, acc5 = 0, acc6 = 0, acc7 = 0;

    __syncthreads();

    #pragma unroll
    for (int chunk = 0; chunk < 2; ++chunk) {
        if (chunk) __syncthreads();

        int r = w * 16 + hrow;
        int src = idx_s[chunk * 64 + r];
        int jglob = chunk * 64 + r;
        f32x4 st = {0.f, 0.f, 0.f, 0.f};
        #pragma unroll 1
        for (int ks = 0; ks < 8; ++ks) {
            bf16x8 af = *(const bf16x8*)(ckvb + (long)src * 256 + ks * 32 + kslice);
            bf16x8 qf = {0, 0, 0, 0, 0, 0, 0, 0};
            if (hrow < 8) {
                const float* qp = qabs + (long)t * 2048 + hrow * 256 + ks * 32 + kslice;
                float4 a = *(const float4*)qp;
                float4 b = *(const float4*)(qp + 4);
                unsigned short qq[8];
                qq[0] = bfu(a.x * scale); qq[1] = bfu(a.y * scale);
                qq[2] = bfu(a.z * scale); qq[3] = bfu(a.w * scale);
                qq[4] = bfu(b.x * scale); qq[5] = bfu(b.y * scale);
                qq[6] = bfu(b.z * scale); qq[7] = bfu(b.w * scale);
                qf = *(bf16x8*)qq;
            }
            st = __builtin_amdgcn_mfma_f32_16x16x32_bf16(af, qf, st, 0, 0, 0);
        }
        {
            int i15 = kslice & 15;
            bool lo = kslice < 16;
            float4 m1a = *(const float4*)(mu + src * 32 + i15);
            float4 m1b = *(const float4*)(mu + src * 32 + i15 + 4);
            float4 m2a = *(const float4*)(mu + src * 32 + 16 + i15);
            float4 m2b = *(const float4*)(mu + src * 32 + 16 + i15 + 4);
            float4 ca = *(const float4*)(csc + jglob * 16 + i15);
            float4 cb = *(const float4*)(csc + jglob * 16 + i15 + 4);
            float4 sa = *(const float4*)(css + jglob * 16 + i15);
            float4 sb = *(const float4*)(css + jglob * 16 + i15 + 4);
            unsigned short hh[8];
            hh[0] = bfu(lo ? m1a.x * ca.x - m2a.x * sa.x : m1a.x * sa.x + m2a.x * ca.x);
            hh[1] = bfu(lo ? m1a.y * ca.y - m2a.y * sa.y : m1a.y * sa.y + m2a.y * ca.y);
            hh[2] = bfu(lo ? m1a.z * ca.z - m2a.z * sa.z : m1a.z * sa.z + m2a.z * ca.z);
            hh[3] = bfu(lo ? m1a.w * ca.w - m2a.w * sa.w : m1a.w * sa.w + m2a.w * ca.w);
            hh[4] = bfu(lo ? m1b.x * cb.x - m2b.x * sb.x : m1b.x * sb.x + m2b.x * cb.x);
            hh[5] = bfu(lo ? m1b.y * cb.y - m2b.y * sb.y : m1b.y * sb.y + m2b.y * cb.y);
            hh[6] = bfu(lo ? m1b.z * cb.z - m2b.z * sb.z : m1b.z * sb.z + m2b.z * cb.z);
            hh[7] = bfu(lo ? m1b.w * cb.w - m2b.w * sb.w : m1b.w * sb.w + m2b.w * cb.w);
            bf16x8 af = *(bf16x8*)hh;
            bf16x8 qf = {0, 0, 0, 0, 0, 0, 0, 0};
            if (hrow < 8) {
                const float* qp = qrr + (long)t * 256 + hrow * 32 + kslice;
                float4 a = *(const float4*)qp;
                float4 b = *(const float4*)(qp + 4);
                unsigned short qq[8];
                qq[0] = bfu(a.x * scale); qq[1] = bfu(a.y * scale);
                qq[2] = bfu(a.z * scale); qq[3] = bfu(a.w * scale);
                qq[4] = bfu(b.x * scale); qq[5] = bfu(b.y * scale);
                qq[6] = bfu(b.z * scale); qq[7] = bfu(b.w * scale);
                qf = *(bf16x8*)qq;
            }
            st = __builtin_amdgcn_mfma_f32_16x16x32_bf16(af, qf, st, 0, 0, 0);
        }
        {
            int srow2 = w * 16 + (l >> 4) * 4;
            if (hrow < 8) {
                #pragma unroll
                for (int rr = 0; rr < 4; ++rr) sc[hrow][srow2 + rr] = st[rr];
            }
        }
        __syncthreads();

        float rh0, rh1;
        {
            int h = 2 * w;
            float v = sc[h][l];
            float mx = v;
            #pragma unroll
            for (int off = 32; off > 0; off >>= 1) mx = fmaxf(mx, __shfl_xor(mx, off));
            float mnew = fmaxf(mrun0, mx);
            float p = expf(v - mnew);
            float ps = p;
            #pragma unroll
            for (int off = 32; off > 0; off >>= 1) ps += __shfl_xor(ps, off);
            rh0 = expf(mrun0 - mnew);
            lrun0 = lrun0 * rh0 + ps;
            mrun0 = mnew;
            sc[h][l] = p;
        }
        {
            int h = 2 * w + 1;
            float v = sc[h][l];
            float mx = v;
            #pragma unroll
            for (int off = 32; off > 0; off >>= 1) mx = fmaxf(mx, __shfl_xor(mx, off));
            float mnew = fmaxf(mrun1, mx);
            float p = expf(v - mnew);
            float ps = p;
            #pragma unroll
            for (int off = 32; off > 0; off >>= 1) ps += __shfl_xor(ps, off);
            rh1 = expf(mrun1 - mnew);
            lrun1 = lrun1 * rh1 + ps;
            mrun1 = mnew;
            sc[h][l] = p;
        }
        if (l == 0) {
            hs[2 * w] = rh0;
            hs[2 * w + 1] = rh1;
            if (chunk == 1) {
                hs[8 + 2 * w] = lrun0;
                hs[8 + 2 * w + 1] = lrun1;
            }
        }
        __syncthreads();

        float rsel = hs[hpv];
        acc0 *= rsel; acc1 *= rsel; acc2 *= rsel; acc3 *= rsel;
        acc4 *= rsel; acc5 *= rsel; acc6 *= rsel; acc7 *= rsel;
        #pragma unroll 4
        for (int j = 0; j < 64; ++j) {
            float p = sc[hpv][j];
            int srcj = idx_s[chunk * 64 + j];
            uint4 vv = *(const uint4*)(ckvb + (long)srcj * 256 + c8);
            acc0 += p * __uint_as_float(vv.x << 16);
            acc1 += p * __uint_as_float(vv.x & 0xffff0000u);
            acc2 += p * __uint_as_float(vv.y << 16);
            acc3 += p * __uint_as_float(vv.y & 0xffff0000u);
            acc4 += p * __uint_as_float(vv.z << 16);
            acc5 += p * __uint_as_float(vv.z & 0xffff0000u);
            acc6 += p * __uint_as_float(vv.w << 16);
            acc7 += p * __uint_as_float(vv.w & 0xffff0000u);
        }
    }

    float inv = 1.f / hs[8 + hpv];
    float* op = olat + (long)t * 2048 + hpv * 256 + c8;
    *(float4*)op       = make_float4(acc0 * inv, acc1 * inv, acc2 * inv, acc3 * inv);
    *(float4*)(op + 4) = make_float4(acc4 * inv, acc5 * inv, acc6 * inv, acc7 * inv);
}

extern "C" void kernel_launch(void* const* d_in, const int* in_sizes, int n_in,
                              void* d_out, int out_size, void* d_ws, size_t ws_size,
                              hipStream_t stream)
{
    const float* x         = (const float*)d_in[0];
    const float* w_q_idx   = (const float*)d_in[1];
    const float* w_k_idx   = (const float*)d_in[2];
    const float* w_idx     = (const float*)d_in[3];
    const float* raw_delta = (const float*)d_in[4];
    const float* w_dkv     = (const float*)d_in[5];
    const float* w_uk      = (const float*)d_in[6];
    const float* w_uv      = (const float*)d_in[7];
    const float* w_dq      = (const float*)d_in[8];
    const float* w_uq      = (const float*)d_in[9];
    const float* w_qr      = (const float*)d_in[10];
    const float* w_kr      = (const float*)d_in[11];
    const float* w_out     = (const float*)d_in[12];
    (void)in_sizes; (void)n_in; (void)out_size; (void)ws_size;
    float* out = (float*)d_out;

    // ---- workspace layout: r12/r16 allocator verbatim (known-good) ----
    float* ws = (float*)d_ws;
    unsigned short* ckvb = (unsigned short*)ws;   ws += 131072;   // 1024x256 bf16
    float* cq    = ws;        ws += 1024 * 512;
    float* xkr   = ws;        ws += 1024 * 32;
    float* qrp   = ws;        ws += 1024 * 256;
    float* qrr   = ws;        ws += 1024 * 256;
    float* qc    = ws;        ws += 1024 * 512;
    float* qabs  = ws;        ws += 1024 * 2048;
    float* Ibuf  = ws;        ws += 1024 * 1024;
    int*   idxb  = (int*)ws;  ws += 1024 * 128;
    float* olat  = ws;        ws += 1024 * 2048;
    float* outh  = ws;        ws += 1024 * 512;
    float* mu    = ws;        ws += 1024 * 32;
    float* cscb  = ws;        ws += 128 * 16;
    float* cssb  = ws;        ws += 128 * 16;
    unsigned short* wdkvT = (unsigned short*)ws;  ws += 131072;
    unsigned short* wdqT  = (unsigned short*)ws;  ws += 262144;
    unsigned short* wkrT  = (unsigned short*)ws;  ws += 16384;
    unsigned short* wuqT  = (unsigned short*)ws;  ws += 131072;
    unsigned short* wqrT  = (unsigned short*)ws;  ws += 65536;
    unsigned short* wuvT  = (unsigned short*)ws;  ws += 65536;
    unsigned short* woutT = (unsigned short*)ws;  ws += 262144;
    unsigned short* wukb  = (unsigned short*)ws;  ws += 65536;
    float* part  = ws;        ws += 2359296;
    float* qIP = part;                  // 4 x 524288
    float* kIP = part + 2097152;        // 4 x 65536

    // ---- L1: PREP (weight tcast + cs + wukb) — weights only
    {
        PREP f{};
        f.raw_delta = raw_delta; f.wuk = w_uk;
        f.wdkv = w_dkv; f.wdq = w_dq; f.wkr = w_kr; f.wuq = w_uq; f.wqr = w_qr;
        f.wuv = w_uv; f.wout = w_out;
        f.csc = cscb; f.css = cssb;
        f.wdkvT = wdkvT; f.wdqT = wdqT; f.wkrT = wkrT; f.wuqT = wuqT;
        f.wqrT = wqrT; f.wuvT = wuvT; f.woutT = woutT; f.wukb = wukb;
        prep_kernel<<<dim3(984), dim3(256), 0, stream>>>(f);
    }

    // ---- L2: SELV = stage-1 value projections (MFMA) + sel-GEMM (VALU fp32)
    {
        SELV g{};
        g.x = x; g.wqidx = w_q_idx; g.wkidx = w_k_idx;
        g.wdkvT = wdkvT; g.wdqT = wdqT; g.wkrT = wkrT;
        g.ckvb = ckvb; g.cq = cq; g.xkr = xkr;
        g.qIP = qIP; g.kIP = kIP;
        selv_kernel<<<dim3(1360), dim3(256), 0, stream>>>(g);
    }

    // ---- L3: S2C = stage-2 projections + indexer
    {
        S2C g{};
        g.cq = cq; g.wuqT = wuqT; g.wqrT = wqrT;
        g.qc = qc; g.qrp = qrp;
        g.qIP = qIP; g.kIP = kIP; g.w_idx = w_idx; g.I = Ibuf;
        s2c_kernel<<<dim3(704), dim3(256), 0, stream>>>(g);
    }

    // ---- L4: MID3 = topk + qabs + pope + mu
    {
        MID3 g{};
        g.I = Ibuf; g.idxb = idxb;
        g.qc = qc; g.wukb = wukb; g.qabs = qabs;
        g.qrp = qrp; g.raw_delta = raw_delta; g.qrr = qrr;
        g.xkr = xkr; g.mu = mu;
        mid3_kernel<<<dim3(1408), dim3(256), 0, stream>>>(g);
    }

    // ---- L5: fused attention v8 -> olat
    attn_kernel<<<dim3(1024), dim3(256), 0, stream>>>(qabs, qrr, ckvb, mu, cscb, cssb, idxb, olat);

    // ---- L6: outh_h = olat_h @ w_uv_h
    {
        MFG m{};
        for (int h = 0; h < 8; ++h) {
            m.A[h] = olat + h * 256;      m.lda[h] = 2048; m.K[h] = 256;
            m.B[h] = wuvT + h * 64 * 256; m.ldb[h] = 256;
            m.C[h] = outh + h * 64;       m.ldc[h] = 512;  m.N[h] = 64;
            m.tstart[h] = h;
        }
        m.tstart[8] = 8;
        m.ne = 8;
        mgemm<<<dim3(8, 16), dim3(256), 0, stream>>>(m);
    }

    // ---- L7: out = outh @ w_out
    {
        MFG m{};
        m.A[0] = outh;  m.lda[0] = 512; m.K[0] = 512;
        m.B[0] = woutT; m.ldb[0] = 512;
        m.C[0] = out;   m.ldc[0] = 1024; m.N[0] = 1024;
        m.tstart[0] = 0; m.tstart[1] = 16;
        m.ne = 1;
        mgemm<<<dim3(16, 16), dim3(256), 0, stream>>>(m);
    }
}

// Round 18
// 163.912 us; speedup vs baseline: 1.0427x; 1.0427x over previous
//
#include <hip/hip_runtime.h>
#include <math.h>

#define S_LEN 1024
#define NH 8

typedef __attribute__((ext_vector_type(8))) short bf16x8;
typedef __attribute__((ext_vector_type(4))) float f32x4;

__device__ __forceinline__ float sp_softplus(float x) {
    return fmaxf(x, 0.f) + log1pf(expf(-fabsf(x)));
}

__device__ __forceinline__ unsigned short bfu(float f) {
    unsigned u = __float_as_uint(f);
    unsigned r = (u + 0x7FFFu + ((u >> 16) & 1u)) >> 16;   // RNE
    return (unsigned short)r;
}

// ============ FRONT mega-kernel: sel-GEMM + weight tcast + cs + wukb =========
struct FRONT {
    const float *x, *wqidx, *wkidx, *raw_delta, *wuk;
    const float *wdkv, *wdq, *wkr, *wuq, *wqr, *wuv, *wout;
    float *qIP, *kIP, *csc, *css;
    unsigned short *wdkvT, *wdqT, *wkrT, *wuqT, *wqrT, *wuvT, *woutT, *wukb;
};

__global__ __launch_bounds__(256) void front_kernel(FRONT f)
{
    __shared__ float As[2][16][18];
    __shared__ float Bs[2][16][68];
    __shared__ unsigned short tile[64][65];
    int bx = blockIdx.x;
    if (bx < 1152) {
        int gx = bx % 18, gy = bx / 18;
        int half = threadIdx.x >> 7;
        int t = threadIdx.x & 127;
        int u = gx * 2 + half;
        const float* B; float* C;
        int ldb, N, n0, kb;
        if (u < 32) {
            B = f.wqidx; ldb = 512; N = 512;
            C = f.qIP + (long)(u >> 3) * 524288;
            n0 = (u & 7) * 64;
            kb = (u >> 3) * 256;
        } else {
            B = f.wkidx; ldb = 64; N = 64;
            C = f.kIP + (long)(u - 32) * 65536;
            n0 = 0;
            kb = (u - 32) * 256;
        }
        int ke = kb + 256;
        int m0 = gy * 16;
        int ar = t >> 2, ak = t & 3;
        int bk = t >> 3, bn = t & 7;
        int ty = t >> 4, tx = t & 15;

        float4 aN = make_float4(0.f, 0.f, 0.f, 0.f);
        if (t < 64) aN = *(const float4*)(f.x + (long)(m0 + ar) * 1024 + kb + ak * 4);
        float4 b0 = *(const float4*)(B + (long)(kb + bk) * ldb + n0 + bn * 4);
        float4 b1 = *(const float4*)(B + (long)(kb + bk) * ldb + n0 + (bn + 8) * 4);
        float acc[2][4] = {};
        for (int k0 = kb; k0 < ke; k0 += 16) {
            if (t < 64) {
                As[half][ak * 4 + 0][ar] = aN.x;
                As[half][ak * 4 + 1][ar] = aN.y;
                As[half][ak * 4 + 2][ar] = aN.z;
                As[half][ak * 4 + 3][ar] = aN.w;
            }
            *(float4*)&Bs[half][bk][bn * 4] = b0;
            *(float4*)&Bs[half][bk][(bn + 8) * 4] = b1;
            __syncthreads();
            if (k0 + 16 < ke) {
                if (t < 64) aN = *(const float4*)(f.x + (long)(m0 + ar) * 1024 + (k0 + 16) + ak * 4);
                b0 = *(const float4*)(B + (long)(k0 + 16 + bk) * ldb + n0 + bn * 4);
                b1 = *(const float4*)(B + (long)(k0 + 16 + bk) * ldb + n0 + (bn + 8) * 4);
            }
            #pragma unroll
            for (int kk = 0; kk < 16; ++kk) {
                float2 a = *(float2*)&As[half][kk][ty * 2];
                float4 b = *(float4*)&Bs[half][kk][tx * 4];
                acc[0][0] += a.x * b.x; acc[0][1] += a.x * b.y;
                acc[0][2] += a.x * b.z; acc[0][3] += a.x * b.w;
                acc[1][0] += a.y * b.x; acc[1][1] += a.y * b.y;
                acc[1][2] += a.y * b.z; acc[1][3] += a.y * b.w;
            }
            __syncthreads();
        }
        #pragma unroll
        for (int i = 0; i < 2; ++i) {
            float4 v = make_float4(acc[i][0], acc[i][1], acc[i][2], acc[i][3]);
            *(float4*)(C + (long)(m0 + ty * 2 + i) * N + n0 + tx * 4) = v;
        }
    } else if (bx < 1616) {
        int b = bx - 1152;
        const float* srcs[7] = {f.wdkv, f.wdq, f.wkr, f.wuq, f.wqr, f.wuv, f.wout};
        unsigned short* dsts[7] = {f.wdkvT, f.wdqT, f.wkrT, f.wuqT, f.wqrT, f.wuvT, f.woutT};
        const int Ns[7]   = {256, 512, 32, 512, 256, 512, 1024};
        const int Klds[7] = {1024, 1024, 1024, 512, 512, 256, 512};
        const int Ntl[7]  = {4, 8, 1, 8, 4, 8, 16};
        const int bst[8]  = {0, 64, 192, 208, 272, 304, 336, 464};
        int e = 0;
        #pragma unroll
        for (int i = 1; i < 7; ++i) if (b >= bst[i]) e = i;
        int lb = b - bst[e];
        int nt = lb % Ntl[e], kt = lb / Ntl[e];
        const float* src = srcs[e];
        unsigned short* dst = dsts[e];
        int N = Ns[e], Kld = Klds[e];
        int k0 = kt * 64, n0 = nt * 64;
        int t = threadIdx.x;
        int c = t & 63, r4 = t >> 6;
        #pragma unroll
        for (int it = 0; it < 16; ++it) {
            int r = it * 4 + r4;
            float v = (n0 + c < N) ? src[(long)(k0 + r) * N + n0 + c] : 0.f;
            tile[r][c] = bfu(v);
        }
        __syncthreads();
        int wq = t & 7;
        #pragma unroll
        for (int itw = 0; itw < 2; ++itw) {
            int wr = itw * 32 + (t >> 3);
            if (n0 + wr < N) {
                unsigned short v[8];
                #pragma unroll
                for (int j = 0; j < 8; ++j) v[j] = tile[wq * 8 + j][wr];
                *(uint4*)(dst + (long)(n0 + wr) * Kld + k0 + wq * 8) = *(uint4*)v;
            }
        }
    } else if (bx < 1624) {
        int idx = (bx - 1616) * 256 + threadIdx.x;
        int j = idx >> 4, i = idx & 15;
        float rd = f.raw_delta[i];
        float delta = -6.283185307179586f * (1.f / (1.f + expf(-rd)));
        float th = exp2f(-(float)i * 0.83048202372184f);
        float ang = (float)j * th + delta;
        float sv, cv;
        sincosf(ang, &sv, &cv);
        f.csc[idx] = cv;
        f.css[idx] = sv;
    } else {
        int idx = (bx - 1624) * 256 + threadIdx.x;
        f.wukb[idx] = bfu(f.wuk[idx]);
    }
}

// ============ bf16 MFMA GEMM body (shared by all value-path stages) ==========
__device__ __forceinline__ void mgemm_body(
    const float* A, const unsigned short* B, float* C,
    int lda, int ldb, int ldc, int K, int N, int obf, int m0, int n0, char* smem)
{
    unsigned short (*As)[40] = (unsigned short(*)[40])smem;
    unsigned short (*Bs)[40] = (unsigned short(*)[40])(smem + 5120);
    int t = threadIdx.x;
    int srow = t >> 2, skq = t & 3;
    int wid = t >> 6, l = t & 63;
    int wm = (wid >> 1) * 32, wn = (wid & 1) * 32;
    int fr = l & 15, fk = (l >> 4) * 8;
    bool bok = (n0 + srow) < N;

    f32x4 acc00 = {0.f, 0.f, 0.f, 0.f};
    f32x4 acc01 = {0.f, 0.f, 0.f, 0.f};
    f32x4 acc10 = {0.f, 0.f, 0.f, 0.f};
    f32x4 acc11 = {0.f, 0.f, 0.f, 0.f};

    for (int k0 = 0; k0 < K; k0 += 32) {
        {
            const float* ap = A + (long)(m0 + srow) * lda + k0 + skq * 8;
            float4 v0 = *(const float4*)ap;
            float4 v1 = *(const float4*)(ap + 4);
            unsigned short* d = &As[srow][skq * 8];
            d[0] = bfu(v0.x); d[1] = bfu(v0.y); d[2] = bfu(v0.z); d[3] = bfu(v0.w);
            d[4] = bfu(v1.x); d[5] = bfu(v1.y); d[6] = bfu(v1.z); d[7] = bfu(v1.w);
        }
        {
            uint4 bv = make_uint4(0u, 0u, 0u, 0u);
            if (bok) bv = *(const uint4*)(B + (long)(n0 + srow) * ldb + k0 + skq * 8);
            *(uint4*)&Bs[srow][skq * 8] = bv;
        }
        __syncthreads();
        bf16x8 a0 = *(bf16x8*)&As[wm + fr][fk];
        bf16x8 a1 = *(bf16x8*)&As[wm + 16 + fr][fk];
        bf16x8 b0 = *(bf16x8*)&Bs[wn + fr][fk];
        bf16x8 b1 = *(bf16x8*)&Bs[wn + 16 + fr][fk];
        acc00 = __builtin_amdgcn_mfma_f32_16x16x32_bf16(a0, b0, acc00, 0, 0, 0);
        acc01 = __builtin_amdgcn_mfma_f32_16x16x32_bf16(a0, b1, acc01, 0, 0, 0);
        acc10 = __builtin_amdgcn_mfma_f32_16x16x32_bf16(a1, b0, acc10, 0, 0, 0);
        acc11 = __builtin_amdgcn_mfma_f32_16x16x32_bf16(a1, b1, acc11, 0, 0, 0);
        __syncthreads();
    }
    int crow = (l >> 4) * 4;
    int col0 = n0 + wn + fr, col1 = n0 + wn + 16 + fr;
    if (obf) {
        unsigned short* Cu = (unsigned short*)C;
        if (col0 < N) {
            #pragma unroll
            for (int r = 0; r < 4; ++r) {
                Cu[(long)(m0 + wm + crow + r) * ldc + col0]      = bfu(acc00[r]);
                Cu[(long)(m0 + wm + 16 + crow + r) * ldc + col0] = bfu(acc10[r]);
            }
        }
        if (col1 < N) {
            #pragma unroll
            for (int r = 0; r < 4; ++r) {
                Cu[(long)(m0 + wm + crow + r) * ldc + col1]      = bfu(acc01[r]);
                Cu[(long)(m0 + wm + 16 + crow + r) * ldc + col1] = bfu(acc11[r]);
            }
        }
    } else {
        if (col0 < N) {
            #pragma unroll
            for (int r = 0; r < 4; ++r) {
                C[(long)(m0 + wm + crow + r) * ldc + col0]      = acc00[r];
                C[(long)(m0 + wm + 16 + crow + r) * ldc + col0] = acc10[r];
            }
        }
        if (col1 < N) {
            #pragma unroll
            for (int r = 0; r < 4; ++r) {
                C[(long)(m0 + wm + crow + r) * ldc + col1]      = acc01[r];
                C[(long)(m0 + wm + 16 + crow + r) * ldc + col1] = acc11[r];
            }
        }
    }
}

// ---- indexer body (fused split-K reduce; bit-identical to r12) --------------
__device__ __forceinline__ void indexer_body(
    const float* qIP, const float* kIP, const float* w_idx, float* I,
    int b, char* smem)
{
    int sb = b % 16, tb = b / 16;
    if (sb * 64 > tb * 32 + 31) return;
    int t0 = tb * 32, s0 = sb * 64;
    float (*ksT)[68] = (float(*)[68])smem;
    float (*qs)[68]  = (float(*)[68])(smem + 17408);
    int t = threadIdx.x;
    {
        int r = t & 63, q = t >> 6;
        #pragma unroll
        for (int u = 0; u < 4; ++u) {
            int c4 = q * 4 + u;
            long off = (long)(s0 + r) * 64 + c4 * 4;
            float4 v = *(const float4*)(kIP + off);
            #pragma unroll
            for (int s = 1; s < 4; ++s) {
                float4 v2 = *(const float4*)(kIP + (long)s * 65536 + off);
                v.x += v2.x; v.y += v2.y; v.z += v2.z; v.w += v2.w;
            }
            ksT[c4 * 4 + 0][r] = v.x;
            ksT[c4 * 4 + 1][r] = v.y;
            ksT[c4 * 4 + 2][r] = v.z;
            ksT[c4 * 4 + 3][r] = v.w;
        }
    }
    int ty = t >> 4, tx = t & 15;
    float accI[2][4] = {};
    for (int h = 0; h < 8; ++h) {
        __syncthreads();
        {
            int r = t >> 3, q = t & 7;
            long base = (long)(t0 + r) * 512 + h * 64;
            #pragma unroll
            for (int half = 0; half < 2; ++half) {
                long off = base + (q + half * 8) * 4;
                float4 a = *(const float4*)(qIP + off);
                #pragma unroll
                for (int s = 1; s < 4; ++s) {
                    float4 a1 = *(const float4*)(qIP + (long)s * 524288 + off);
                    a.x += a1.x; a.y += a1.y; a.z += a1.z; a.w += a1.w;
                }
                *(float4*)&qs[r][(q + half * 8) * 4] = a;
            }
        }
        __syncthreads();
        float acc[2][4] = {};
        #pragma unroll
        for (int dc = 0; dc < 4; ++dc) {
            float a0[16], a1[16];
            #pragma unroll
            for (int u = 0; u < 4; ++u) {
                float4 v0 = *(float4*)&qs[ty * 2][dc * 16 + u * 4];
                float4 v1 = *(float4*)&qs[ty * 2 + 1][dc * 16 + u * 4];
                a0[u * 4 + 0] = v0.x; a0[u * 4 + 1] = v0.y; a0[u * 4 + 2] = v0.z; a0[u * 4 + 3] = v0.w;
                a1[u * 4 + 0] = v1.x; a1[u * 4 + 1] = v1.y; a1[u * 4 + 2] = v1.z; a1[u * 4 + 3] = v1.w;
            }
            #pragma unroll
            for (int kk = 0; kk < 16; ++kk) {
                int d = dc * 16 + kk;
                float4 bb = *(float4*)&ksT[d][tx * 4];
                acc[0][0] += a0[kk] * bb.x; acc[0][1] += a0[kk] * bb.y;
                acc[0][2] += a0[kk] * bb.z; acc[0][3] += a0[kk] * bb.w;
                acc[1][0] += a1[kk] * bb.x; acc[1][1] += a1[kk] * bb.y;
                acc[1][2] += a1[kk] * bb.z; acc[1][3] += a1[kk] * bb.w;
            }
        }
        float wh = w_idx[h];
        #pragma unroll
        for (int i = 0; i < 2; ++i)
            #pragma unroll
            for (int j = 0; j < 4; ++j)
                accI[i][j] += wh * fmaxf(acc[i][j], 0.f);
    }
    #pragma unroll
    for (int i = 0; i < 2; ++i) {
        float4 v = make_float4(accI[i][0], accI[i][1], accI[i][2], accI[i][3]);
        *(float4*)&I[(long)(t0 + ty * 2 + i) * 1024 + s0 + tx * 4] = v;
    }
}

// ---- topk body: full wave bitonic sort (bit-identical to r12) ---------------
__device__ __forceinline__ void topk_body(
    const float* I, int* idxout, int b)
{
    int t = b * 4 + (threadIdx.x >> 6);
    int lane = threadIdx.x & 63;
    int smin = max(0, t - 63);
    int w = min(64, t + 1);
    if (lane < w) idxout[t * 128 + lane] = smin + lane;
    for (int q = t + 1 + lane; q < 128; q += 64)
        idxout[t * 128 + q] = q;
    int f = max(0, t - 63);
    int m = min(f, 64);
    if (m == 0) return;
    const float* row = I + (long)t * 1024;

    unsigned long long key[16];
    #pragma unroll
    for (int g4 = 0; g4 < 4; ++g4) {
        float4 v = *(const float4*)(row + lane * 16 + g4 * 4);
        float vv[4] = {v.x, v.y, v.z, v.w};
        #pragma unroll
        for (int j = 0; j < 4; ++j) {
            int s = lane * 16 + g4 * 4 + j;
            unsigned long long k = 0ull;
            if (s < f) {
                unsigned u = __float_as_uint(vv[j]);
                unsigned ou = (u & 0x80000000u) ? ~u : (u | 0x80000000u);
                k = ((unsigned long long)ou << 32) | (0xFFFFFFFFu - (unsigned)s);
            }
            key[g4 * 4 + j] = k;
        }
    }

    #pragma unroll
    for (int km = 1; km <= 10; ++km) {
        #pragma unroll
        for (int jm = km - 1; jm >= 0; --jm) {
            if (jm >= 4) {
                int lmask = 1 << (jm - 4);
                #pragma unroll
                for (int r = 0; r < 16; ++r) {
                    unsigned long long other = __shfl_xor(key[r], lmask, 64);
                    int i = lane * 16 + r;
                    bool keep_max = (((i & (1 << km)) == 0) == ((i & (1 << jm)) == 0));
                    unsigned long long mx = key[r] > other ? key[r] : other;
                    unsigned long long mn = key[r] > other ? other : key[r];
                    key[r] = keep_max ? mx : mn;
                }
            } else {
                int rmask = 1 << jm;
                #pragma unroll
                for (int r = 0; r < 16; ++r) {
                    if ((r & rmask) == 0) {
                        int r2 = r | rmask;
                        int i = lane * 16 + r;
                        bool keep_max_low = ((i & (1 << km)) == 0);
                        unsigned long long a = key[r], b2 = key[r2];
                        unsigned long long mx = a > b2 ? a : b2;
                        unsigned long long mn = a > b2 ? b2 : a;
                        key[r]  = keep_max_low ? mx : mn;
                        key[r2] = keep_max_low ? mn : mx;
                    }
                }
            }
        }
    }

    if (lane < 4) {
        #pragma unroll
        for (int r = 0; r < 16; ++r) {
            int e = lane * 16 + r;
            if (e < m) {
                int s = (int)(0xFFFFFFFFu - (unsigned)(key[r] & 0xFFFFFFFFull));
                idxout[t * 128 + w + e] = s;
            }
        }
    }
}

// ============ S1: stage-1 value mgemm (208) + indexer (512) = 720 blocks =====
struct S1ARG {
    const float* x;
    const unsigned short *wdkvT, *wdqT, *wkrT;
    unsigned short* ckvb; float *cq, *xkr;
    const float *qIP, *kIP, *w_idx; float* I;
};

__global__ __launch_bounds__(256) void s1_kernel(S1ARG g)
{
    __shared__ __align__(16) char smem[26112];
    int bx = blockIdx.x;
    if (bx < 208) {
        int xi = bx % 13, m0 = (bx / 13) * 64;
        if (xi < 4)       mgemm_body(g.x, g.wdkvT, (float*)g.ckvb, 1024, 1024, 256, 1024, 256, 1, m0, xi * 64, smem);
        else if (xi < 12) mgemm_body(g.x, g.wdqT,  g.cq,           1024, 1024, 512, 1024, 512, 0, m0, (xi - 4) * 64, smem);
        else              mgemm_body(g.x, g.wkrT,  g.xkr,          1024, 1024, 32,  1024, 32,  0, m0, 0, smem);
    } else {
        indexer_body(g.qIP, g.kIP, g.w_idx, g.I, bx - 208, smem);
    }
}

// ============ S2: stage-2 mgemm (192) + topk (256) = 448 blocks ==============
struct S2ARG {
    const float* cq;
    const unsigned short *wuqT, *wqrT;
    float *qc, *qrp;
    const float* I; int* idxb;
};

__global__ __launch_bounds__(256) void s2_kernel(S2ARG g)
{
    __shared__ __align__(16) char smem[10240];
    int bx = blockIdx.x;
    if (bx < 192) {
        int xi = bx % 12, m0 = (bx / 12) * 64;
        if (xi < 8) mgemm_body(g.cq, g.wuqT, g.qc,  512, 512, 512, 512, 512, 0, m0, xi * 64, smem);
        else        mgemm_body(g.cq, g.wqrT, g.qrp, 512, 512, 256, 512, 256, 0, m0, (xi - 8) * 64, smem);
    } else {
        topk_body(g.I, g.idxb, bx - 192);
    }
}

// ============ MID2: qabs (512) + pope (512) + mu (128) = 1152 blocks =========
struct MID2 {
    const float* qc; const unsigned short* wukb; float* qabs;
    const float *qrp, *raw_delta; float* qrr;
    const float* xkr; float* mu;
};

__global__ __launch_bounds__(256) void mid2_kernel(MID2 g)
{
    __shared__ __align__(16) char smem[10240];
    int b = blockIdx.x;
    int t = threadIdx.x;
    if (b < 512) {
        int h = b >> 6, rem = b & 63;
        int n0 = (rem >> 4) * 64, m0 = (rem & 15) * 64;
        mgemm_body(g.qc + h * 64, g.wukb + h * 64, g.qabs + h * 256,
                   512, 512, 2048, 64, 256, 0, m0, n0, smem);
    } else if (b < 1024) {
        int tq = (b - 512) * 2 + (t >> 7);
        int tt = t & 127;
        int h = tt >> 4, i = tt & 15;
        float rd = g.raw_delta[i];
        float delta = -6.283185307179586f * (1.f / (1.f + expf(-rd)));
        float th = exp2f(-(float)i * 0.83048202372184f);
        float ang = (float)tq * th + delta;
        float sv, cv;
        sincosf(ang, &sv, &cv);
        float m1 = sp_softplus(g.qrp[tq * 256 + h * 32 + i]);
        float m2 = sp_softplus(g.qrp[tq * 256 + h * 32 + 16 + i]);
        g.qrr[tq * 256 + h * 32 + i]      = m1 * cv - m2 * sv;
        g.qrr[tq * 256 + h * 32 + 16 + i] = m1 * sv + m2 * cv;
    } else {
        int i = (b - 1024) * 256 + t;
        g.mu[i] = sp_softplus(g.xkr[i]);
    }
}

// ============ generic routed mgemm kernel (L6/L7) ============================
struct MFG {
    const float* A[10]; const unsigned short* B[10]; float* C[10];
    int lda[10], ldb[10], ldc[10], K[10], N[10], obf[10];
    int tstart[11]; int ne;
};

__global__ __launch_bounds__(256) void mgemm(MFG mg)
{
    __shared__ __align__(16) char smem[10240];
    int bx = blockIdx.x, e = 0;
    #pragma unroll
    for (int i = 1; i < 10; ++i) if (i < mg.ne && bx >= mg.tstart[i]) e = i;
    mgemm_body(mg.A[e], mg.B[e], mg.C[e], mg.lda[e], mg.ldb[e], mg.ldc[e],
               mg.K[e], mg.N[e], mg.obf[e], blockIdx.y * 64,
               (bx - mg.tstart[e]) * 64, smem);
}

// -------- fused attention v8 (r12 verbatim — best measured: 46.7 us) ---------
__global__ __launch_bounds__(256) void attn_kernel(
    const float* __restrict__ qabs, const float* __restrict__ qrr,
    const unsigned short* __restrict__ ckvb, const float* __restrict__ mu,
    const float* __restrict__ csc, const float* __restrict__ css,
    const int* __restrict__ idxb, float* __restrict__ olat)
{
    __shared__ float sc[8][68];
    __shared__ float hs[16];
    __shared__ int idx_s[128];

    int t = blockIdx.x, tid = threadIdx.x;
    int w = tid >> 6, l = tid & 63;
    const float scale = 0.10206207261596575f;

    if (tid < 128) idx_s[tid] = idxb[t * 128 + tid];

    int hrow = l & 15;
    int kslice = (l >> 4) * 8;
    int hpv = l >> 3;
    int c8 = w * 64 + (l & 7) * 8;

    float mrun0 = -INFINITY, mrun1 = -INFINITY;
    float lrun0 = 0.f, lrun1 = 0.f;
    float acc0 = 0, acc1 = 0, acc2 = 0, acc3 = 0;
    float acc4 = 0, acc5 = 0, acc6 = 0, acc7 = 0;

    __syncthreads();

    #pragma unroll
    for (int chunk = 0; chunk < 2; ++chunk) {
        if (chunk) __syncthreads();

        int r = w * 16 + hrow;
        int src = idx_s[chunk * 64 + r];
        int jglob = chunk * 64 + r;
        f32x4 st = {0.f, 0.f, 0.f, 0.f};
        #pragma unroll 1
        for (int ks = 0; ks < 8; ++ks) {
            bf16x8 af = *(const bf16x8*)(ckvb + (long)src * 256 + ks * 32 + kslice);
            bf16x8 qf = {0, 0, 0, 0, 0, 0, 0, 0};
            if (hrow < 8) {
                const float* qp = qabs + (long)t * 2048 + hrow * 256 + ks * 32 + kslice;
                float4 a = *(const float4*)qp;
                float4 b = *(const float4*)(qp + 4);
                unsigned short qq[8];
                qq[0] = bfu(a.x * scale); qq[1] = bfu(a.y * scale);
                qq[2] = bfu(a.z * scale); qq[3] = bfu(a.w * scale);
                qq[4] = bfu(b.x * scale); qq[5] = bfu(b.y * scale);
                qq[6] = bfu(b.z * scale); qq[7] = bfu(b.w * scale);
                qf = *(bf16x8*)qq;
            }
            st = __builtin_amdgcn_mfma_f32_16x16x32_bf16(af, qf, st, 0, 0, 0);
        }
        {
            int i15 = kslice & 15;
            bool lo = kslice < 16;
            float4 m1a = *(const float4*)(mu + src * 32 + i15);
            float4 m1b = *(const float4*)(mu + src * 32 + i15 + 4);
            float4 m2a = *(const float4*)(mu + src * 32 + 16 + i15);
            float4 m2b = *(const float4*)(mu + src * 32 + 16 + i15 + 4);
            float4 ca = *(const float4*)(csc + jglob * 16 + i15);
            float4 cb = *(const float4*)(csc + jglob * 16 + i15 + 4);
            float4 sa = *(const float4*)(css + jglob * 16 + i15);
            float4 sb = *(const float4*)(css + jglob * 16 + i15 + 4);
            unsigned short hh[8];
            hh[0] = bfu(lo ? m1a.x * ca.x - m2a.x * sa.x : m1a.x * sa.x + m2a.x * ca.x);
            hh[1] = bfu(lo ? m1a.y * ca.y - m2a.y * sa.y : m1a.y * sa.y + m2a.y * ca.y);
            hh[2] = bfu(lo ? m1a.z * ca.z - m2a.z * sa.z : m1a.z * sa.z + m2a.z * ca.z);
            hh[3] = bfu(lo ? m1a.w * ca.w - m2a.w * sa.w : m1a.w * sa.w + m2a.w * ca.w);
            hh[4] = bfu(lo ? m1b.x * cb.x - m2b.x * sb.x : m1b.x * sb.x + m2b.x * cb.x);
            hh[5] = bfu(lo ? m1b.y * cb.y - m2b.y * sb.y : m1b.y * sb.y + m2b.y * cb.y);
            hh[6] = bfu(lo ? m1b.z * cb.z - m2b.z * sb.z : m1b.z * sb.z + m2b.z * cb.z);
            hh[7] = bfu(lo ? m1b.w * cb.w - m2b.w * sb.w : m1b.w * sb.w + m2b.w * cb.w);
            bf16x8 af = *(bf16x8*)hh;
            bf16x8 qf = {0, 0, 0, 0, 0, 0, 0, 0};
            if (hrow < 8) {
                const float* qp = qrr + (long)t * 256 + hrow * 32 + kslice;
                float4 a = *(const float4*)qp;
                float4 b = *(const float4*)(qp + 4);
                unsigned short qq[8];
                qq[0] = bfu(a.x * scale); qq[1] = bfu(a.y * scale);
                qq[2] = bfu(a.z * scale); qq[3] = bfu(a.w * scale);
                qq[4] = bfu(b.x * scale); qq[5] = bfu(b.y * scale);
                qq[6] = bfu(b.z * scale); qq[7] = bfu(b.w * scale);
                qf = *(bf16x8*)qq;
            }
            st = __builtin_amdgcn_mfma_f32_16x16x32_bf16(af, qf, st, 0, 0, 0);
        }
        {
            int srow2 = w * 16 + (l >> 4) * 4;
            if (hrow < 8) {
                #pragma unroll
                for (int rr = 0; rr < 4; ++rr) sc[hrow][srow2 + rr] = st[rr];
            }
        }
        __syncthreads();

        float rh0, rh1;
        {
            int h = 2 * w;
            float v = sc[h][l];
            float mx = v;
            #pragma unroll
            for (int off = 32; off > 0; off >>= 1) mx = fmaxf(mx, __shfl_xor(mx, off));
            float mnew = fmaxf(mrun0, mx);
            float p = expf(v - mnew);
            float ps = p;
            #pragma unroll
            for (int off = 32; off > 0; off >>= 1) ps += __shfl_xor(ps, off);
            rh0 = expf(mrun0 - mnew);
            lrun0 = lrun0 * rh0 + ps;
            mrun0 = mnew;
            sc[h][l] = p;
        }
        {
            int h = 2 * w + 1;
            float v = sc[h][l];
            float mx = v;
            #pragma unroll
            for (int off = 32; off > 0; off >>= 1) mx = fmaxf(mx, __shfl_xor(mx, off));
            float mnew = fmaxf(mrun1, mx);
            float p = expf(v - mnew);
            float ps = p;
            #pragma unroll
            for (int off = 32; off > 0; off >>= 1) ps += __shfl_xor(ps, off);
            rh1 = expf(mrun1 - mnew);
            lrun1 = lrun1 * rh1 + ps;
            mrun1 = mnew;
            sc[h][l] = p;
        }
        if (l == 0) {
            hs[2 * w] = rh0;
            hs[2 * w + 1] = rh1;
            if (chunk == 1) {
                hs[8 + 2 * w] = lrun0;
                hs[8 + 2 * w + 1] = lrun1;
            }
        }
        __syncthreads();

        float rsel = hs[hpv];
        acc0 *= rsel; acc1 *= rsel; acc2 *= rsel; acc3 *= rsel;
        acc4 *= rsel; acc5 *= rsel; acc6 *= rsel; acc7 *= rsel;
        #pragma unroll 4
        for (int j = 0; j < 64; ++j) {
            float p = sc[hpv][j];
            int srcj = idx_s[chunk * 64 + j];
            uint4 vv = *(const uint4*)(ckvb + (long)srcj * 256 + c8);
            acc0 += p * __uint_as_float(vv.x << 16);
            acc1 += p * __uint_as_float(vv.x & 0xffff0000u);
            acc2 += p * __uint_as_float(vv.y << 16);
            acc3 += p * __uint_as_float(vv.y & 0xffff0000u);
            acc4 += p * __uint_as_float(vv.z << 16);
            acc5 += p * __uint_as_float(vv.z & 0xffff0000u);
            acc6 += p * __uint_as_float(vv.w << 16);
            acc7 += p * __uint_as_float(vv.w & 0xffff0000u);
        }
    }

    float inv = 1.f / hs[8 + hpv];
    float* op = olat + (long)t * 2048 + hpv * 256 + c8;
    *(float4*)op       = make_float4(acc0 * inv, acc1 * inv, acc2 * inv, acc3 * inv);
    *(float4*)(op + 4) = make_float4(acc4 * inv, acc5 * inv, acc6 * inv, acc7 * inv);
}

extern "C" void kernel_launch(void* const* d_in, const int* in_sizes, int n_in,
                              void* d_out, int out_size, void* d_ws, size_t ws_size,
                              hipStream_t stream)
{
    const float* x         = (const float*)d_in[0];
    const float* w_q_idx   = (const float*)d_in[1];
    const float* w_k_idx   = (const float*)d_in[2];
    const float* w_idx     = (const float*)d_in[3];
    const float* raw_delta = (const float*)d_in[4];
    const float* w_dkv     = (const float*)d_in[5];
    const float* w_uk      = (const float*)d_in[6];
    const float* w_uv      = (const float*)d_in[7];
    const float* w_dq      = (const float*)d_in[8];
    const float* w_uq      = (const float*)d_in[9];
    const float* w_qr      = (const float*)d_in[10];
    const float* w_kr      = (const float*)d_in[11];
    const float* w_out     = (const float*)d_in[12];
    (void)in_sizes; (void)n_in; (void)out_size; (void)ws_size;
    float* out = (float*)d_out;

    // ---- workspace layout: r12 allocator verbatim (known-good) ----
    float* ws = (float*)d_ws;
    unsigned short* ckvb = (unsigned short*)ws;   ws += 131072;   // 1024x256 bf16
    float* cq    = ws;        ws += 1024 * 512;
    float* xkr   = ws;        ws += 1024 * 32;
    float* qrp   = ws;        ws += 1024 * 256;
    float* qrr   = ws;        ws += 1024 * 256;
    float* qc    = ws;        ws += 1024 * 512;
    float* qabs  = ws;        ws += 1024 * 2048;
    float* Ibuf  = ws;        ws += 1024 * 1024;
    int*   idxb  = (int*)ws;  ws += 1024 * 128;
    float* olat  = ws;        ws += 1024 * 2048;
    float* outh  = ws;        ws += 1024 * 512;
    float* mu    = ws;        ws += 1024 * 32;
    float* cscb  = ws;        ws += 128 * 16;
    float* cssb  = ws;        ws += 128 * 16;
    unsigned short* wdkvT = (unsigned short*)ws;  ws += 131072;
    unsigned short* wdqT  = (unsigned short*)ws;  ws += 262144;
    unsigned short* wkrT  = (unsigned short*)ws;  ws += 16384;
    unsigned short* wuqT  = (unsigned short*)ws;  ws += 131072;
    unsigned short* wqrT  = (unsigned short*)ws;  ws += 65536;
    unsigned short* wuvT  = (unsigned short*)ws;  ws += 65536;
    unsigned short* woutT = (unsigned short*)ws;  ws += 262144;
    unsigned short* wukb  = (unsigned short*)ws;  ws += 65536;
    float* part  = ws;        ws += 2359296;
    float* qIP = part;                  // 4 x 524288
    float* kIP = part + 2097152;        // 4 x 65536

    // ---- L1: FRONT (sel GEMM + weight tcast + cs + wukb)
    {
        FRONT f{};
        f.x = x; f.wqidx = w_q_idx; f.wkidx = w_k_idx; f.raw_delta = raw_delta; f.wuk = w_uk;
        f.wdkv = w_dkv; f.wdq = w_dq; f.wkr = w_kr; f.wuq = w_uq; f.wqr = w_qr;
        f.wuv = w_uv; f.wout = w_out;
        f.qIP = qIP; f.kIP = kIP; f.csc = cscb; f.css = cssb;
        f.wdkvT = wdkvT; f.wdqT = wdqT; f.wkrT = wkrT; f.wuqT = wuqT;
        f.wqrT = wqrT; f.wuvT = wuvT; f.woutT = woutT; f.wukb = wukb;
        front_kernel<<<dim3(2136), dim3(256), 0, stream>>>(f);
    }

    // ---- L2: S1 = stage-1 value projections + indexer (one launch)
    {
        S1ARG g{};
        g.x = x; g.wdkvT = wdkvT; g.wdqT = wdqT; g.wkrT = wkrT;
        g.ckvb = ckvb; g.cq = cq; g.xkr = xkr;
        g.qIP = qIP; g.kIP = kIP; g.w_idx = w_idx; g.I = Ibuf;
        s1_kernel<<<dim3(720), dim3(256), 0, stream>>>(g);
    }

    // ---- L3: S2 = stage-2 projections + topk (one launch)
    {
        S2ARG g{};
        g.cq = cq; g.wuqT = wuqT; g.wqrT = wqrT;
        g.qc = qc; g.qrp = qrp;
        g.I = Ibuf; g.idxb = idxb;
        s2_kernel<<<dim3(448), dim3(256), 0, stream>>>(g);
    }

    // ---- L4: MID2 = qabs + pope + mu
    {
        MID2 g{};
        g.qc = qc; g.wukb = wukb; g.qabs = qabs;
        g.qrp = qrp; g.raw_delta = raw_delta; g.qrr = qrr;
        g.xkr = xkr; g.mu = mu;
        mid2_kernel<<<dim3(1152), dim3(256), 0, stream>>>(g);
    }

    // ---- L5: fused attention v8 -> olat
    attn_kernel<<<dim3(1024), dim3(256), 0, stream>>>(qabs, qrr, ckvb, mu, cscb, cssb, idxb, olat);

    // ---- L6: outh_h = olat_h @ w_uv_h
    {
        MFG m{};
        for (int h = 0; h < 8; ++h) {
            m.A[h] = olat + h * 256;      m.lda[h] = 2048; m.K[h] = 256;
            m.B[h] = wuvT + h * 64 * 256; m.ldb[h] = 256;
            m.C[h] = outh + h * 64;       m.ldc[h] = 512;  m.N[h] = 64;
            m.tstart[h] = h;
        }
        m.tstart[8] = 8;
        m.ne = 8;
        mgemm<<<dim3(8, 16), dim3(256), 0, stream>>>(m);
    }

    // ---- L7: out = outh @ w_out
    {
        MFG m{};
        m.A[0] = outh;  m.lda[0] = 512; m.K[0] = 512;
        m.B[0] = woutT; m.ldb[0] = 512;
        m.C[0] = out;   m.ldc[0] = 1024; m.N[0] = 1024;
        m.tstart[0] = 0; m.tstart[1] = 16;
        m.ne = 1;
        mgemm<<<dim3(16, 16), dim3(256), 0, stream>>>(m);
    }
}

// Round 19
// 158.289 us; speedup vs baseline: 1.0797x; 1.0355x over previous
//
#include <hip/hip_runtime.h>
#include <math.h>

#define S_LEN 1024
#define NH 8

typedef __attribute__((ext_vector_type(8))) short bf16x8;
typedef __attribute__((ext_vector_type(4))) float f32x4;

__device__ __forceinline__ float sp_softplus(float x) {
    return fmaxf(x, 0.f) + log1pf(expf(-fabsf(x)));
}

__device__ __forceinline__ unsigned short bfu(float f) {
    unsigned u = __float_as_uint(f);
    unsigned r = (u + 0x7FFFu + ((u >> 16) & 1u)) >> 16;   // RNE
    return (unsigned short)r;
}

// ============ FRONT mega-kernel: sel-GEMM (64x64/4x4) + tcast + cs + wukb ====
// blocks [0,576): fp32 sel GEMM — qI (512: slab ks=u>>7, nt=(u&127)>>4,
//   mt=u&15), kI (64: v=u-512, ks=v>>4, mt=v&15). Per-output fmac chain is
//   k-ascending with the same KS=4 slab split -> bit-identical selection.
// blocks [576,1040): tcast; [1040,1048): cs table; [1048,1560): wukb cast.
struct FRONT {
    const float *x, *wqidx, *wkidx, *raw_delta, *wuk;
    const float *wdkv, *wdq, *wkr, *wuq, *wqr, *wuv, *wout;
    float *qIP, *kIP, *csc, *css;
    unsigned short *wdkvT, *wdqT, *wkrT, *wuqT, *wqrT, *wuvT, *woutT, *wukb;
};

__global__ __launch_bounds__(256) void front_kernel(FRONT f)
{
    __shared__ __align__(16) char smem[8704];
    int bx = blockIdx.x;
    if (bx < 576) {
        float (*AsF)[68] = (float(*)[68])smem;           // [16][68]
        float (*BsF)[68] = (float(*)[68])(smem + 4352);  // [16][68]
        int u = bx;
        const float* B; float* C;
        int ldb, N, n0, kb, m0;
        if (u < 512) {
            int ks = u >> 7, rem = u & 127;
            B = f.wqidx; ldb = 512; N = 512;
            C = f.qIP + (long)ks * 524288;
            n0 = (rem >> 4) * 64;
            m0 = (rem & 15) * 64;
            kb = ks * 256;
        } else {
            int v = u - 512;
            int ks = v >> 4;
            B = f.wkidx; ldb = 64; N = 64;
            C = f.kIP + (long)ks * 65536;
            n0 = 0;
            m0 = (v & 15) * 64;
            kb = ks * 256;
        }
        int ke = kb + 256;
        int t = threadIdx.x;
        int ar = t >> 2, aq = t & 3;     // A staging: row ar, k-quad aq
        int br = t >> 4, bc = t & 15;    // B staging: k-row br, col-quad bc
        int ty = t >> 4, tx = t & 15;    // compute: rows ty*4.., cols tx*4..

        float4 aN = *(const float4*)(f.x + (long)(m0 + ar) * 1024 + kb + aq * 4);
        float4 bN = *(const float4*)(B + (long)(kb + br) * ldb + n0 + bc * 4);
        float acc[4][4] = {};
        for (int k0 = kb; k0 < ke; k0 += 16) {
            AsF[aq * 4 + 0][ar] = aN.x;
            AsF[aq * 4 + 1][ar] = aN.y;
            AsF[aq * 4 + 2][ar] = aN.z;
            AsF[aq * 4 + 3][ar] = aN.w;
            *(float4*)&BsF[br][bc * 4] = bN;
            __syncthreads();
            if (k0 + 16 < ke) {
                aN = *(const float4*)(f.x + (long)(m0 + ar) * 1024 + (k0 + 16) + aq * 4);
                bN = *(const float4*)(B + (long)(k0 + 16 + br) * ldb + n0 + bc * 4);
            }
            #pragma unroll
            for (int kk = 0; kk < 16; ++kk) {
                float4 a = *(float4*)&AsF[kk][ty * 4];
                float4 b = *(float4*)&BsF[kk][tx * 4];
                acc[0][0] += a.x * b.x; acc[0][1] += a.x * b.y; acc[0][2] += a.x * b.z; acc[0][3] += a.x * b.w;
                acc[1][0] += a.y * b.x; acc[1][1] += a.y * b.y; acc[1][2] += a.y * b.z; acc[1][3] += a.y * b.w;
                acc[2][0] += a.z * b.x; acc[2][1] += a.z * b.y; acc[2][2] += a.z * b.z; acc[2][3] += a.z * b.w;
                acc[3][0] += a.w * b.x; acc[3][1] += a.w * b.y; acc[3][2] += a.w * b.z; acc[3][3] += a.w * b.w;
            }
            __syncthreads();
        }
        #pragma unroll
        for (int i = 0; i < 4; ++i) {
            float4 v = make_float4(acc[i][0], acc[i][1], acc[i][2], acc[i][3]);
            *(float4*)(C + (long)(m0 + ty * 4 + i) * N + n0 + tx * 4) = v;
        }
    } else if (bx < 1040) {
        unsigned short (*tile)[65] = (unsigned short(*)[65])smem;
        int b = bx - 576;
        const float* srcs[7] = {f.wdkv, f.wdq, f.wkr, f.wuq, f.wqr, f.wuv, f.wout};
        unsigned short* dsts[7] = {f.wdkvT, f.wdqT, f.wkrT, f.wuqT, f.wqrT, f.wuvT, f.woutT};
        const int Ns[7]   = {256, 512, 32, 512, 256, 512, 1024};
        const int Klds[7] = {1024, 1024, 1024, 512, 512, 256, 512};
        const int Ntl[7]  = {4, 8, 1, 8, 4, 8, 16};
        const int bst[8]  = {0, 64, 192, 208, 272, 304, 336, 464};
        int e = 0;
        #pragma unroll
        for (int i = 1; i < 7; ++i) if (b >= bst[i]) e = i;
        int lb = b - bst[e];
        int nt = lb % Ntl[e], kt = lb / Ntl[e];
        const float* src = srcs[e];
        unsigned short* dst = dsts[e];
        int N = Ns[e], Kld = Klds[e];
        int k0 = kt * 64, n0 = nt * 64;
        int t = threadIdx.x;
        int c = t & 63, r4 = t >> 6;
        #pragma unroll
        for (int it = 0; it < 16; ++it) {
            int r = it * 4 + r4;
            float v = (n0 + c < N) ? src[(long)(k0 + r) * N + n0 + c] : 0.f;
            tile[r][c] = bfu(v);
        }
        __syncthreads();
        int wq = t & 7;
        #pragma unroll
        for (int itw = 0; itw < 2; ++itw) {
            int wr = itw * 32 + (t >> 3);
            if (n0 + wr < N) {
                unsigned short v[8];
                #pragma unroll
                for (int j = 0; j < 8; ++j) v[j] = tile[wq * 8 + j][wr];
                *(uint4*)(dst + (long)(n0 + wr) * Kld + k0 + wq * 8) = *(uint4*)v;
            }
        }
    } else if (bx < 1048) {
        int idx = (bx - 1040) * 256 + threadIdx.x;
        int j = idx >> 4, i = idx & 15;
        float rd = f.raw_delta[i];
        float delta = -6.283185307179586f * (1.f / (1.f + expf(-rd)));
        float th = exp2f(-(float)i * 0.83048202372184f);
        float ang = (float)j * th + delta;
        float sv, cv;
        sincosf(ang, &sv, &cv);
        f.csc[idx] = cv;
        f.css[idx] = sv;
    } else {
        int idx = (bx - 1048) * 256 + threadIdx.x;
        f.wukb[idx] = bfu(f.wuk[idx]);
    }
}

// ============ bf16 MFMA GEMM body (shared by all value-path stages) ==========
__device__ __forceinline__ void mgemm_body(
    const float* A, const unsigned short* B, float* C,
    int lda, int ldb, int ldc, int K, int N, int obf, int m0, int n0, char* smem)
{
    unsigned short (*As)[40] = (unsigned short(*)[40])smem;
    unsigned short (*Bs)[40] = (unsigned short(*)[40])(smem + 5120);
    int t = threadIdx.x;
    int srow = t >> 2, skq = t & 3;
    int wid = t >> 6, l = t & 63;
    int wm = (wid >> 1) * 32, wn = (wid & 1) * 32;
    int fr = l & 15, fk = (l >> 4) * 8;
    bool bok = (n0 + srow) < N;

    f32x4 acc00 = {0.f, 0.f, 0.f, 0.f};
    f32x4 acc01 = {0.f, 0.f, 0.f, 0.f};
    f32x4 acc10 = {0.f, 0.f, 0.f, 0.f};
    f32x4 acc11 = {0.f, 0.f, 0.f, 0.f};

    for (int k0 = 0; k0 < K; k0 += 32) {
        {
            const float* ap = A + (long)(m0 + srow) * lda + k0 + skq * 8;
            float4 v0 = *(const float4*)ap;
            float4 v1 = *(const float4*)(ap + 4);
            unsigned short* d = &As[srow][skq * 8];
            d[0] = bfu(v0.x); d[1] = bfu(v0.y); d[2] = bfu(v0.z); d[3] = bfu(v0.w);
            d[4] = bfu(v1.x); d[5] = bfu(v1.y); d[6] = bfu(v1.z); d[7] = bfu(v1.w);
        }
        {
            uint4 bv = make_uint4(0u, 0u, 0u, 0u);
            if (bok) bv = *(const uint4*)(B + (long)(n0 + srow) * ldb + k0 + skq * 8);
            *(uint4*)&Bs[srow][skq * 8] = bv;
        }
        __syncthreads();
        bf16x8 a0 = *(bf16x8*)&As[wm + fr][fk];
        bf16x8 a1 = *(bf16x8*)&As[wm + 16 + fr][fk];
        bf16x8 b0 = *(bf16x8*)&Bs[wn + fr][fk];
        bf16x8 b1 = *(bf16x8*)&Bs[wn + 16 + fr][fk];
        acc00 = __builtin_amdgcn_mfma_f32_16x16x32_bf16(a0, b0, acc00, 0, 0, 0);
        acc01 = __builtin_amdgcn_mfma_f32_16x16x32_bf16(a0, b1, acc01, 0, 0, 0);
        acc10 = __builtin_amdgcn_mfma_f32_16x16x32_bf16(a1, b0, acc10, 0, 0, 0);
        acc11 = __builtin_amdgcn_mfma_f32_16x16x32_bf16(a1, b1, acc11, 0, 0, 0);
        __syncthreads();
    }
    int crow = (l >> 4) * 4;
    int col0 = n0 + wn + fr, col1 = n0 + wn + 16 + fr;
    if (obf) {
        unsigned short* Cu = (unsigned short*)C;
        if (col0 < N) {
            #pragma unroll
            for (int r = 0; r < 4; ++r) {
                Cu[(long)(m0 + wm + crow + r) * ldc + col0]      = bfu(acc00[r]);
                Cu[(long)(m0 + wm + 16 + crow + r) * ldc + col0] = bfu(acc10[r]);
            }
        }
        if (col1 < N) {
            #pragma unroll
            for (int r = 0; r < 4; ++r) {
                Cu[(long)(m0 + wm + crow + r) * ldc + col1]      = bfu(acc01[r]);
                Cu[(long)(m0 + wm + 16 + crow + r) * ldc + col1] = bfu(acc11[r]);
            }
        }
    } else {
        if (col0 < N) {
            #pragma unroll
            for (int r = 0; r < 4; ++r) {
                C[(long)(m0 + wm + crow + r) * ldc + col0]      = acc00[r];
                C[(long)(m0 + wm + 16 + crow + r) * ldc + col0] = acc10[r];
            }
        }
        if (col1 < N) {
            #pragma unroll
            for (int r = 0; r < 4; ++r) {
                C[(long)(m0 + wm + crow + r) * ldc + col1]      = acc01[r];
                C[(long)(m0 + wm + 16 + crow + r) * ldc + col1] = acc11[r];
            }
        }
    }
}

// ---- indexer body (fused split-K reduce; bit-identical) ---------------------
__device__ __forceinline__ void indexer_body(
    const float* qIP, const float* kIP, const float* w_idx, float* I,
    int b, char* smem)
{
    int sb = b % 16, tb = b / 16;
    if (sb * 64 > tb * 32 + 31) return;
    int t0 = tb * 32, s0 = sb * 64;
    float (*ksT)[68] = (float(*)[68])smem;
    float (*qs)[68]  = (float(*)[68])(smem + 17408);
    int t = threadIdx.x;
    {
        int r = t & 63, q = t >> 6;
        #pragma unroll
        for (int u = 0; u < 4; ++u) {
            int c4 = q * 4 + u;
            long off = (long)(s0 + r) * 64 + c4 * 4;
            float4 v = *(const float4*)(kIP + off);
            #pragma unroll
            for (int s = 1; s < 4; ++s) {
                float4 v2 = *(const float4*)(kIP + (long)s * 65536 + off);
                v.x += v2.x; v.y += v2.y; v.z += v2.z; v.w += v2.w;
            }
            ksT[c4 * 4 + 0][r] = v.x;
            ksT[c4 * 4 + 1][r] = v.y;
            ksT[c4 * 4 + 2][r] = v.z;
            ksT[c4 * 4 + 3][r] = v.w;
        }
    }
    int ty = t >> 4, tx = t & 15;
    float accI[2][4] = {};
    for (int h = 0; h < 8; ++h) {
        __syncthreads();
        {
            int r = t >> 3, q = t & 7;
            long base = (long)(t0 + r) * 512 + h * 64;
            #pragma unroll
            for (int half = 0; half < 2; ++half) {
                long off = base + (q + half * 8) * 4;
                float4 a = *(const float4*)(qIP + off);
                #pragma unroll
                for (int s = 1; s < 4; ++s) {
                    float4 a1 = *(const float4*)(qIP + (long)s * 524288 + off);
                    a.x += a1.x; a.y += a1.y; a.z += a1.z; a.w += a1.w;
                }
                *(float4*)&qs[r][(q + half * 8) * 4] = a;
            }
        }
        __syncthreads();
        float acc[2][4] = {};
        #pragma unroll
        for (int dc = 0; dc < 4; ++dc) {
            float a0[16], a1[16];
            #pragma unroll
            for (int u = 0; u < 4; ++u) {
                float4 v0 = *(float4*)&qs[ty * 2][dc * 16 + u * 4];
                float4 v1 = *(float4*)&qs[ty * 2 + 1][dc * 16 + u * 4];
                a0[u * 4 + 0] = v0.x; a0[u * 4 + 1] = v0.y; a0[u * 4 + 2] = v0.z; a0[u * 4 + 3] = v0.w;
                a1[u * 4 + 0] = v1.x; a1[u * 4 + 1] = v1.y; a1[u * 4 + 2] = v1.z; a1[u * 4 + 3] = v1.w;
            }
            #pragma unroll
            for (int kk = 0; kk < 16; ++kk) {
                int d = dc * 16 + kk;
                float4 bb = *(float4*)&ksT[d][tx * 4];
                acc[0][0] += a0[kk] * bb.x; acc[0][1] += a0[kk] * bb.y;
                acc[0][2] += a0[kk] * bb.z; acc[0][3] += a0[kk] * bb.w;
                acc[1][0] += a1[kk] * bb.x; acc[1][1] += a1[kk] * bb.y;
                acc[1][2] += a1[kk] * bb.z; acc[1][3] += a1[kk] * bb.w;
            }
        }
        float wh = w_idx[h];
        #pragma unroll
        for (int i = 0; i < 2; ++i)
            #pragma unroll
            for (int j = 0; j < 4; ++j)
                accI[i][j] += wh * fmaxf(acc[i][j], 0.f);
    }
    #pragma unroll
    for (int i = 0; i < 2; ++i) {
        float4 v = make_float4(accI[i][0], accI[i][1], accI[i][2], accI[i][3]);
        *(float4*)&I[(long)(t0 + ty * 2 + i) * 1024 + s0 + tx * 4] = v;
    }
}

// ---- topk body: full wave bitonic sort (bit-identical) ----------------------
__device__ __forceinline__ void topk_body(
    const float* I, int* idxout, int b)
{
    int t = b * 4 + (threadIdx.x >> 6);
    int lane = threadIdx.x & 63;
    int smin = max(0, t - 63);
    int w = min(64, t + 1);
    if (lane < w) idxout[t * 128 + lane] = smin + lane;
    for (int q = t + 1 + lane; q < 128; q += 64)
        idxout[t * 128 + q] = q;
    int f = max(0, t - 63);
    int m = min(f, 64);
    if (m == 0) return;
    const float* row = I + (long)t * 1024;

    unsigned long long key[16];
    #pragma unroll
    for (int g4 = 0; g4 < 4; ++g4) {
        float4 v = *(const float4*)(row + lane * 16 + g4 * 4);
        float vv[4] = {v.x, v.y, v.z, v.w};
        #pragma unroll
        for (int j = 0; j < 4; ++j) {
            int s = lane * 16 + g4 * 4 + j;
            unsigned long long k = 0ull;
            if (s < f) {
                unsigned u = __float_as_uint(vv[j]);
                unsigned ou = (u & 0x80000000u) ? ~u : (u | 0x80000000u);
                k = ((unsigned long long)ou << 32) | (0xFFFFFFFFu - (unsigned)s);
            }
            key[g4 * 4 + j] = k;
        }
    }

    #pragma unroll
    for (int km = 1; km <= 10; ++km) {
        #pragma unroll
        for (int jm = km - 1; jm >= 0; --jm) {
            if (jm >= 4) {
                int lmask = 1 << (jm - 4);
                #pragma unroll
                for (int r = 0; r < 16; ++r) {
                    unsigned long long other = __shfl_xor(key[r], lmask, 64);
                    int i = lane * 16 + r;
                    bool keep_max = (((i & (1 << km)) == 0) == ((i & (1 << jm)) == 0));
                    unsigned long long mx = key[r] > other ? key[r] : other;
                    unsigned long long mn = key[r] > other ? other : key[r];
                    key[r] = keep_max ? mx : mn;
                }
            } else {
                int rmask = 1 << jm;
                #pragma unroll
                for (int r = 0; r < 16; ++r) {
                    if ((r & rmask) == 0) {
                        int r2 = r | rmask;
                        int i = lane * 16 + r;
                        bool keep_max_low = ((i & (1 << km)) == 0);
                        unsigned long long a = key[r], b2 = key[r2];
                        unsigned long long mx = a > b2 ? a : b2;
                        unsigned long long mn = a > b2 ? b2 : a;
                        key[r]  = keep_max_low ? mx : mn;
                        key[r2] = keep_max_low ? mn : mx;
                    }
                }
            }
        }
    }

    if (lane < 4) {
        #pragma unroll
        for (int r = 0; r < 16; ++r) {
            int e = lane * 16 + r;
            if (e < m) {
                int s = (int)(0xFFFFFFFFu - (unsigned)(key[r] & 0xFFFFFFFFull));
                idxout[t * 128 + w + e] = s;
            }
        }
    }
}

// ============ S1: stage-1 value mgemm (208) + indexer (512) = 720 blocks =====
struct S1ARG {
    const float* x;
    const unsigned short *wdkvT, *wdqT, *wkrT;
    unsigned short* ckvb; float *cq, *xkr;
    const float *qIP, *kIP, *w_idx; float* I;
};

__global__ __launch_bounds__(256) void s1_kernel(S1ARG g)
{
    __shared__ __align__(16) char smem[26112];
    int bx = blockIdx.x;
    if (bx < 208) {
        int xi = bx % 13, m0 = (bx / 13) * 64;
        if (xi < 4)       mgemm_body(g.x, g.wdkvT, (float*)g.ckvb, 1024, 1024, 256, 1024, 256, 1, m0, xi * 64, smem);
        else if (xi < 12) mgemm_body(g.x, g.wdqT,  g.cq,           1024, 1024, 512, 1024, 512, 0, m0, (xi - 4) * 64, smem);
        else              mgemm_body(g.x, g.wkrT,  g.xkr,          1024, 1024, 32,  1024, 32,  0, m0, 0, smem);
    } else {
        indexer_body(g.qIP, g.kIP, g.w_idx, g.I, bx - 208, smem);
    }
}

// ============ S2: stage-2 mgemm (192) + topk (256) = 448 blocks ==============
struct S2ARG {
    const float* cq;
    const unsigned short *wuqT, *wqrT;
    float *qc, *qrp;
    const float* I; int* idxb;
};

__global__ __launch_bounds__(256) void s2_kernel(S2ARG g)
{
    __shared__ __align__(16) char smem[10240];
    int bx = blockIdx.x;
    if (bx < 192) {
        int xi = bx % 12, m0 = (bx / 12) * 64;
        if (xi < 8) mgemm_body(g.cq, g.wuqT, g.qc,  512, 512, 512, 512, 512, 0, m0, xi * 64, smem);
        else        mgemm_body(g.cq, g.wqrT, g.qrp, 512, 512, 256, 512, 256, 0, m0, (xi - 8) * 64, smem);
    } else {
        topk_body(g.I, g.idxb, bx - 192);
    }
}

// ============ MID2: qabs (512) + pope (512) + mu (128) = 1152 blocks =========
struct MID2 {
    const float* qc; const unsigned short* wukb; float* qabs;
    const float *qrp, *raw_delta; float* qrr;
    const float* xkr; float* mu;
};

__global__ __launch_bounds__(256) void mid2_kernel(MID2 g)
{
    __shared__ __align__(16) char smem[10240];
    int b = blockIdx.x;
    int t = threadIdx.x;
    if (b < 512) {
        int h = b >> 6, rem = b & 63;
        int n0 = (rem >> 4) * 64, m0 = (rem & 15) * 64;
        mgemm_body(g.qc + h * 64, g.wukb + h * 64, g.qabs + h * 256,
                   512, 512, 2048, 64, 256, 0, m0, n0, smem);
    } else if (b < 1024) {
        int tq = (b - 512) * 2 + (t >> 7);
        int tt = t & 127;
        int h = tt >> 4, i = tt & 15;
        float rd = g.raw_delta[i];
        float delta = -6.283185307179586f * (1.f / (1.f + expf(-rd)));
        float th = exp2f(-(float)i * 0.83048202372184f);
        float ang = (float)tq * th + delta;
        float sv, cv;
        sincosf(ang, &sv, &cv);
        float m1 = sp_softplus(g.qrp[tq * 256 + h * 32 + i]);
        float m2 = sp_softplus(g.qrp[tq * 256 + h * 32 + 16 + i]);
        g.qrr[tq * 256 + h * 32 + i]      = m1 * cv - m2 * sv;
        g.qrr[tq * 256 + h * 32 + 16 + i] = m1 * sv + m2 * cv;
    } else {
        int i = (b - 1024) * 256 + t;
        g.mu[i] = sp_softplus(g.xkr[i]);
    }
}

// ============ generic routed mgemm kernel (L6/L7) ============================
struct MFG {
    const float* A[10]; const unsigned short* B[10]; float* C[10];
    int lda[10], ldb[10], ldc[10], K[10], N[10], obf[10];
    int tstart[11]; int ne;
};

__global__ __launch_bounds__(256) void mgemm(MFG mg)
{
    __shared__ __align__(16) char smem[10240];
    int bx = blockIdx.x, e = 0;
    #pragma unroll
    for (int i = 1; i < 10; ++i) if (i < mg.ne && bx >= mg.tstart[i]) e = i;
    mgemm_body(mg.A[e], mg.B[e], mg.C[e], mg.lda[e], mg.ldb[e], mg.ldc[e],
               mg.K[e], mg.N[e], mg.obf[e], blockIdx.y * 64,
               (bx - mg.tstart[e]) * 64, smem);
}

// -------- fused attention v8 (r12 verbatim — best measured: 46.7 us) ---------
__global__ __launch_bounds__(256) void attn_kernel(
    const float* __restrict__ qabs, const float* __restrict__ qrr,
    const unsigned short* __restrict__ ckvb, const float* __restrict__ mu,
    const float* __restrict__ csc, const float* __restrict__ css,
    const int* __restrict__ idxb, float* __restrict__ olat)
{
    __shared__ float sc[8][68];
    __shared__ float hs[16];
    __shared__ int idx_s[128];

    int t = blockIdx.x, tid = threadIdx.x;
    int w = tid >> 6, l = tid & 63;
    const float scale = 0.10206207261596575f;

    if (tid < 128) idx_s[tid] = idxb[t * 128 + tid];

    int hrow = l & 15;
    int kslice = (l >> 4) * 8;
    int hpv = l >> 3;
    int c8 = w * 64 + (l & 7) * 8;

    float mrun0 = -INFINITY, mrun1 = -INFINITY;
    float lrun0 = 0.f, lrun1 = 0.f;
    float acc0 = 0, acc1 = 0, acc2 = 0, acc3 = 0;
    float acc4 = 0, acc5 = 0, acc6 = 0, acc7 = 0;

    __syncthreads();

    #pragma unroll
    for (int chunk = 0; chunk < 2; ++chunk) {
        if (chunk) __syncthreads();

        int r = w * 16 + hrow;
        int src = idx_s[chunk * 64 + r];
        int jglob = chunk * 64 + r;
        f32x4 st = {0.f, 0.f, 0.f, 0.f};
        #pragma unroll 1
        for (int ks = 0; ks < 8; ++ks) {
            bf16x8 af = *(const bf16x8*)(ckvb + (long)src * 256 + ks * 32 + kslice);
            bf16x8 qf = {0, 0, 0, 0, 0, 0, 0, 0};
            if (hrow < 8) {
                const float* qp = qabs + (long)t * 2048 + hrow * 256 + ks * 32 + kslice;
                float4 a = *(const float4*)qp;
                float4 b = *(const float4*)(qp + 4);
                unsigned short qq[8];
                qq[0] = bfu(a.x * scale); qq[1] = bfu(a.y * scale);
                qq[2] = bfu(a.z * scale); qq[3] = bfu(a.w * scale);
                qq[4] = bfu(b.x * scale); qq[5] = bfu(b.y * scale);
                qq[6] = bfu(b.z * scale); qq[7] = bfu(b.w * scale);
                qf = *(bf16x8*)qq;
            }
            st = __builtin_amdgcn_mfma_f32_16x16x32_bf16(af, qf, st, 0, 0, 0);
        }
        {
            int i15 = kslice & 15;
            bool lo = kslice < 16;
            float4 m1a = *(const float4*)(mu + src * 32 + i15);
            float4 m1b = *(const float4*)(mu + src * 32 + i15 + 4);
            float4 m2a = *(const float4*)(mu + src * 32 + 16 + i15);
            float4 m2b = *(const float4*)(mu + src * 32 + 16 + i15 + 4);
            float4 ca = *(const float4*)(csc + jglob * 16 + i15);
            float4 cb = *(const float4*)(csc + jglob * 16 + i15 + 4);
            float4 sa = *(const float4*)(css + jglob * 16 + i15);
            float4 sb = *(const float4*)(css + jglob * 16 + i15 + 4);
            unsigned short hh[8];
            hh[0] = bfu(lo ? m1a.x * ca.x - m2a.x * sa.x : m1a.x * sa.x + m2a.x * ca.x);
            hh[1] = bfu(lo ? m1a.y * ca.y - m2a.y * sa.y : m1a.y * sa.y + m2a.y * ca.y);
            hh[2] = bfu(lo ? m1a.z * ca.z - m2a.z * sa.z : m1a.z * sa.z + m2a.z * ca.z);
            hh[3] = bfu(lo ? m1a.w * ca.w - m2a.w * sa.w : m1a.w * sa.w + m2a.w * ca.w);
            hh[4] = bfu(lo ? m1b.x * cb.x - m2b.x * sb.x : m1b.x * sb.x + m2b.x * cb.x);
            hh[5] = bfu(lo ? m1b.y * cb.y - m2b.y * sb.y : m1b.y * sb.y + m2b.y * cb.y);
            hh[6] = bfu(lo ? m1b.z * cb.z - m2b.z * sb.z : m1b.z * sb.z + m2b.z * cb.z);
            hh[7] = bfu(lo ? m1b.w * cb.w - m2b.w * sb.w : m1b.w * sb.w + m2b.w * cb.w);
            bf16x8 af = *(bf16x8*)hh;
            bf16x8 qf = {0, 0, 0, 0, 0, 0, 0, 0};
            if (hrow < 8) {
                const float* qp = qrr + (long)t * 256 + hrow * 32 + kslice;
                float4 a = *(const float4*)qp;
                float4 b = *(const float4*)(qp + 4);
                unsigned short qq[8];
                qq[0] = bfu(a.x * scale); qq[1] = bfu(a.y * scale);
                qq[2] = bfu(a.z * scale); qq[3] = bfu(a.w * scale);
                qq[4] = bfu(b.x * scale); qq[5] = bfu(b.y * scale);
                qq[6] = bfu(b.z * scale); qq[7] = bfu(b.w * scale);
                qf = *(bf16x8*)qq;
            }
            st = __builtin_amdgcn_mfma_f32_16x16x32_bf16(af, qf, st, 0, 0, 0);
        }
        {
            int srow2 = w * 16 + (l >> 4) * 4;
            if (hrow < 8) {
                #pragma unroll
                for (int rr = 0; rr < 4; ++rr) sc[hrow][srow2 + rr] = st[rr];
            }
        }
        __syncthreads();

        float rh0, rh1;
        {
            int h = 2 * w;
            float v = sc[h][l];
            float mx = v;
            #pragma unroll
            for (int off = 32; off > 0; off >>= 1) mx = fmaxf(mx, __shfl_xor(mx, off));
            float mnew = fmaxf(mrun0, mx);
            float p = expf(v - mnew);
            float ps = p;
            #pragma unroll
            for (int off = 32; off > 0; off >>= 1) ps += __shfl_xor(ps, off);
            rh0 = expf(mrun0 - mnew);
            lrun0 = lrun0 * rh0 + ps;
            mrun0 = mnew;
            sc[h][l] = p;
        }
        {
            int h = 2 * w + 1;
            float v = sc[h][l];
            float mx = v;
            #pragma unroll
            for (int off = 32; off > 0; off >>= 1) mx = fmaxf(mx, __shfl_xor(mx, off));
            float mnew = fmaxf(mrun1, mx);
            float p = expf(v - mnew);
            float ps = p;
            #pragma unroll
            for (int off = 32; off > 0; off >>= 1) ps += __shfl_xor(ps, off);
            rh1 = expf(mrun1 - mnew);
            lrun1 = lrun1 * rh1 + ps;
            mrun1 = mnew;
            sc[h][l] = p;
        }
        if (l == 0) {
            hs[2 * w] = rh0;
            hs[2 * w + 1] = rh1;
            if (chunk == 1) {
                hs[8 + 2 * w] = lrun0;
                hs[8 + 2 * w + 1] = lrun1;
            }
        }
        __syncthreads();

        float rsel = hs[hpv];
        acc0 *= rsel; acc1 *= rsel; acc2 *= rsel; acc3 *= rsel;
        acc4 *= rsel; acc5 *= rsel; acc6 *= rsel; acc7 *= rsel;
        #pragma unroll 4
        for (int j = 0; j < 64; ++j) {
            float p = sc[hpv][j];
            int srcj = idx_s[chunk * 64 + j];
            uint4 vv = *(const uint4*)(ckvb + (long)srcj * 256 + c8);
            acc0 += p * __uint_as_float(vv.x << 16);
            acc1 += p * __uint_as_float(vv.x & 0xffff0000u);
            acc2 += p * __uint_as_float(vv.y << 16);
            acc3 += p * __uint_as_float(vv.y & 0xffff0000u);
            acc4 += p * __uint_as_float(vv.z << 16);
            acc5 += p * __uint_as_float(vv.z & 0xffff0000u);
            acc6 += p * __uint_as_float(vv.w << 16);
            acc7 += p * __uint_as_float(vv.w & 0xffff0000u);
        }
    }

    float inv = 1.f / hs[8 + hpv];
    float* op = olat + (long)t * 2048 + hpv * 256 + c8;
    *(float4*)op       = make_float4(acc0 * inv, acc1 * inv, acc2 * inv, acc3 * inv);
    *(float4*)(op + 4) = make_float4(acc4 * inv, acc5 * inv, acc6 * inv, acc7 * inv);
}

extern "C" void kernel_launch(void* const* d_in, const int* in_sizes, int n_in,
                              void* d_out, int out_size, void* d_ws, size_t ws_size,
                              hipStream_t stream)
{
    const float* x         = (const float*)d_in[0];
    const float* w_q_idx   = (const float*)d_in[1];
    const float* w_k_idx   = (const float*)d_in[2];
    const float* w_idx     = (const float*)d_in[3];
    const float* raw_delta = (const float*)d_in[4];
    const float* w_dkv     = (const float*)d_in[5];
    const float* w_uk      = (const float*)d_in[6];
    const float* w_uv      = (const float*)d_in[7];
    const float* w_dq      = (const float*)d_in[8];
    const float* w_uq      = (const float*)d_in[9];
    const float* w_qr      = (const float*)d_in[10];
    const float* w_kr      = (const float*)d_in[11];
    const float* w_out     = (const float*)d_in[12];
    (void)in_sizes; (void)n_in; (void)out_size; (void)ws_size;
    float* out = (float*)d_out;

    // ---- workspace layout: r12 allocator verbatim (known-good) ----
    float* ws = (float*)d_ws;
    unsigned short* ckvb = (unsigned short*)ws;   ws += 131072;   // 1024x256 bf16
    float* cq    = ws;        ws += 1024 * 512;
    float* xkr   = ws;        ws += 1024 * 32;
    float* qrp   = ws;        ws += 1024 * 256;
    float* qrr   = ws;        ws += 1024 * 256;
    float* qc    = ws;        ws += 1024 * 512;
    float* qabs  = ws;        ws += 1024 * 2048;
    float* Ibuf  = ws;        ws += 1024 * 1024;
    int*   idxb  = (int*)ws;  ws += 1024 * 128;
    float* olat  = ws;        ws += 1024 * 2048;
    float* outh  = ws;        ws += 1024 * 512;
    float* mu    = ws;        ws += 1024 * 32;
    float* cscb  = ws;        ws += 128 * 16;
    float* cssb  = ws;        ws += 128 * 16;
    unsigned short* wdkvT = (unsigned short*)ws;  ws += 131072;
    unsigned short* wdqT  = (unsigned short*)ws;  ws += 262144;
    unsigned short* wkrT  = (unsigned short*)ws;  ws += 16384;
    unsigned short* wuqT  = (unsigned short*)ws;  ws += 131072;
    unsigned short* wqrT  = (unsigned short*)ws;  ws += 65536;
    unsigned short* wuvT  = (unsigned short*)ws;  ws += 65536;
    unsigned short* woutT = (unsigned short*)ws;  ws += 262144;
    unsigned short* wukb  = (unsigned short*)ws;  ws += 65536;
    float* part  = ws;        ws += 2359296;
    float* qIP = part;                  // 4 x 524288
    float* kIP = part + 2097152;        // 4 x 65536

    // ---- L1: FRONT (sel GEMM 64x64/4x4 + weight tcast + cs + wukb)
    {
        FRONT f{};
        f.x = x; f.wqidx = w_q_idx; f.wkidx = w_k_idx; f.raw_delta = raw_delta; f.wuk = w_uk;
        f.wdkv = w_dkv; f.wdq = w_dq; f.wkr = w_kr; f.wuq = w_uq; f.wqr = w_qr;
        f.wuv = w_uv; f.wout = w_out;
        f.qIP = qIP; f.kIP = kIP; f.csc = cscb; f.css = cssb;
        f.wdkvT = wdkvT; f.wdqT = wdqT; f.wkrT = wkrT; f.wuqT = wuqT;
        f.wqrT = wqrT; f.wuvT = wuvT; f.woutT = woutT; f.wukb = wukb;
        front_kernel<<<dim3(1560), dim3(256), 0, stream>>>(f);
    }

    // ---- L2: S1 = stage-1 value projections + indexer (one launch)
    {
        S1ARG g{};
        g.x = x; g.wdkvT = wdkvT; g.wdqT = wdqT; g.wkrT = wkrT;
        g.ckvb = ckvb; g.cq = cq; g.xkr = xkr;
        g.qIP = qIP; g.kIP = kIP; g.w_idx = w_idx; g.I = Ibuf;
        s1_kernel<<<dim3(720), dim3(256), 0, stream>>>(g);
    }

    // ---- L3: S2 = stage-2 projections + topk (one launch)
    {
        S2ARG g{};
        g.cq = cq; g.wuqT = wuqT; g.wqrT = wqrT;
        g.qc = qc; g.qrp = qrp;
        g.I = Ibuf; g.idxb = idxb;
        s2_kernel<<<dim3(448), dim3(256), 0, stream>>>(g);
    }

    // ---- L4: MID2 = qabs + pope + mu
    {
        MID2 g{};
        g.qc = qc; g.wukb = wukb; g.qabs = qabs;
        g.qrp = qrp; g.raw_delta = raw_delta; g.qrr = qrr;
        g.xkr = xkr; g.mu = mu;
        mid2_kernel<<<dim3(1152), dim3(256), 0, stream>>>(g);
    }

    // ---- L5: fused attention v8 -> olat
    attn_kernel<<<dim3(1024), dim3(256), 0, stream>>>(qabs, qrr, ckvb, mu, cscb, cssb, idxb, olat);

    // ---- L6: outh_h = olat_h @ w_uv_h
    {
        MFG m{};
        for (int h = 0; h < 8; ++h) {
            m.A[h] = olat + h * 256;      m.lda[h] = 2048; m.K[h] = 256;
            m.B[h] = wuvT + h * 64 * 256; m.ldb[h] = 256;
            m.C[h] = outh + h * 64;       m.ldc[h] = 512;  m.N[h] = 64;
            m.tstart[h] = h;
        }
        m.tstart[8] = 8;
        m.ne = 8;
        mgemm<<<dim3(8, 16), dim3(256), 0, stream>>>(m);
    }

    // ---- L7: out = outh @ w_out
    {
        MFG m{};
        m.A[0] = outh;  m.lda[0] = 512; m.K[0] = 512;
        m.B[0] = woutT; m.ldb[0] = 512;
        m.C[0] = out;   m.ldc[0] = 1024; m.N[0] = 1024;
        m.tstart[0] = 0; m.tstart[1] = 16;
        m.ne = 1;
        mgemm<<<dim3(16, 16), dim3(256), 0, stream>>>(m);
    }
}